// Round 1
// baseline (1070.853 us; speedup 1.0000x reference)
//
#include <hip/hip_runtime.h>
#include <cstdint>
#include <cstddef>

typedef __attribute__((ext_vector_type(8))) short short8;
typedef __attribute__((ext_vector_type(4))) float floatx4;
typedef unsigned short u16;
typedef unsigned long long u64;

union FragAB { short8 s; u64 q[2]; };
struct L16 { u64 lo, hi; };

__device__ __forceinline__ float bf2f(u16 u) {
  union { unsigned int i; float f; } v; v.i = ((unsigned int)u) << 16; return v.f;
}
__device__ __forceinline__ u16 f2bf(float f) {
  union { float f; unsigned int u; } v; v.f = f;
  return (u16)((v.u + 0x7fffu + ((v.u >> 16) & 1u)) >> 16);
}
__device__ __forceinline__ void bfp(unsigned int p, float& x, float& y) {
  union { unsigned int i; float f; } a, b;
  a.i = p << 16; b.i = p & 0xffff0000u;
  x = a.f; y = b.f;
}
__device__ __forceinline__ unsigned int packbf(float a, float b) {
  return (unsigned int)f2bf(a) | ((unsigned int)f2bf(b) << 16);
}
__device__ __forceinline__ u64 pack4(float a, float b, float c, float d) {
  return (u64)f2bf(a) | ((u64)f2bf(b) << 16) | ((u64)f2bf(c) << 32) | ((u64)f2bf(d) << 48);
}

// ---------------- DCT-II orthonormal 56x56 matrix (fp32) ----------------
__global__ __launch_bounds__(256) void k_dctmat(float* __restrict__ Wd) {
  int i = blockIdx.x * 256 + threadIdx.x;
  if (i < 56 * 56) {
    int n = i / 56, x = i - n * 56;
    float v = cosf(3.14159265358979323846f * (float)n * ((float)x + 0.5f) / 56.0f)
              * 0.1889822365046136f;            // sqrt(2/56)
    if (n == 0) v *= 0.7071067811865476f;
    Wd[i] = v;
  }
}

// ---------------- depthwise conv 3x3, NCHW fp32 -> channel-last bf16 ----------------
__global__ __launch_bounds__(256) void k_conv(const float* __restrict__ x,
                                              const float* __restrict__ w9,
                                              const float* __restrict__ b1,
                                              u16* __restrict__ hbf) {
  __shared__ float xs[64 * 177];  // [c][3 rows][59 cols], col 0 <-> gx=-1
  const int y = blockIdx.x, c0 = blockIdx.y * 64, b = blockIdx.z;
  const int tid = threadIdx.x, cl = tid & 63, wv = tid >> 6;
  float wr[9];
  #pragma unroll
  for (int k = 0; k < 9; ++k) wr[k] = w9[(c0 + cl) * 9 + k];
  const float br = b1[c0 + cl];
  for (int it = 0; it < 48; ++it) {
    int combo = it * 4 + wv;             // 0..191 -> (c, r)
    int c = combo / 3, r = combo - c * 3;
    int col = tid & 63;
    if (col < 58) {
      int gy = y + r - 1, gx = col - 1;
      float v = 0.f;
      if (gy >= 0 && gy < 56 && gx >= 0 && gx < 56)
        v = x[(((size_t)b * 384 + c0 + c) * 56 + gy) * 56 + gx];
      xs[c * 177 + r * 59 + col] = v;
    }
  }
  __syncthreads();
  for (int it = 0; it < 14; ++it) {
    int px = it * 4 + wv;
    float a = br;
    #pragma unroll
    for (int dy = 0; dy < 3; ++dy)
      #pragma unroll
      for (int dx = 0; dx < 3; ++dx)
        a += wr[dy * 3 + dx] * xs[cl * 177 + dy * 59 + px + dx];
    hbf[((size_t)b * 3136 + y * 56 + px) * 384 + c0 + cl] = f2bf(a);
  }
}

// ---------------- restructured MFMA mainloop ----------------
// Block computes a 64-row slice of the LARGE ("outer") operand against the
// FULL 384 of the small ("multi") operand: outer staged ONCE per K-step,
// multi's three 128-wide tiles cycle through two LDS buffers.
// C[m][n] = sum_k A[m,k]*B[n,k], K=384.
#define LDA 68
#define TS 132
#define SH_U16 (64 * LDA + 2 * 128 * LDA)   // 21760 u16 = 43520 B

template<bool F32, int ROWS>
__device__ __forceinline__ void stage_tile(const void* __restrict__ P, int base, int kt,
                                           u16* __restrict__ buf, int srow, int sc8) {
  #pragma unroll
  for (int p = 0; p < ROWS / 32; ++p) {
    int row = srow + p * 32;
    if constexpr (F32) {
      const float4* s = (const float4*)((const float*)P + (size_t)(base + row) * 384 + kt + sc8 * 8);
      float4 v0 = s[0], v1 = s[1];
      *(u64*)&buf[row * LDA + sc8 * 8]     = pack4(v0.x, v0.y, v0.z, v0.w);
      *(u64*)&buf[row * LDA + sc8 * 8 + 4] = pack4(v1.x, v1.y, v1.z, v1.w);
    } else {
      L16 v = *(const L16*)((const u16*)P + (size_t)(base + row) * 384 + kt + sc8 * 8);
      *(u64*)&buf[row * LDA + sc8 * 8]     = v.lo;
      *(u64*)&buf[row * LDA + sc8 * 8 + 4] = v.hi;
    }
  }
}

// A-side rows of C come from Aside buffer, B-side cols from Bside buffer.
// MULTI_A: multi operand (128-row tiles) is the MFMA A-side; else outer (64 rows) is.
template<bool MULTI_A, int NI, int NJ>
__device__ __forceinline__ void comp_tile(const u16* __restrict__ Os, const u16* __restrict__ Ms,
                                          floatx4 acc[NI][NJ], int wm, int wn, int q, int l15) {
  const u16* Aside = MULTI_A ? Ms : Os;
  const u16* Bside = MULTI_A ? Os : Ms;
  constexpr int AW = MULTI_A ? 64 : 32;   // per-wave row stride on A-side
  constexpr int BW = MULTI_A ? 32 : 64;   // per-wave col stride on B-side
  #pragma unroll
  for (int kc = 0; kc < 64; kc += 32) {
    FragAB af[NI], bf[NJ];
    #pragma unroll
    for (int i = 0; i < NI; ++i) {
      int ra = (wm * AW + i * 16 + l15) * LDA + kc + q * 8;
      af[i].q[0] = *(const u64*)&Aside[ra];
      af[i].q[1] = *(const u64*)&Aside[ra + 4];
    }
    #pragma unroll
    for (int j = 0; j < NJ; ++j) {
      int rb = (wn * BW + j * 16 + l15) * LDA + kc + q * 8;
      bf[j].q[0] = *(const u64*)&Bside[rb];
      bf[j].q[1] = *(const u64*)&Bside[rb + 4];
    }
    #pragma unroll
    for (int i = 0; i < NI; ++i)
      #pragma unroll
      for (int j = 0; j < NJ; ++j)
        acc[i][j] = __builtin_amdgcn_mfma_f32_16x16x32_bf16(af[i].s, bf[j].s, acc[i][j], 0, 0, 0);
  }
}

template<bool OF32, bool MF32, bool MULTI_A, int NI, int NJ>
__device__ __forceinline__ void gemm3(const void* __restrict__ Op, const void* __restrict__ Mp,
                                      int o0, int mb,
                                      u16* Os, u16* Ms0, u16* Ms1,
                                      floatx4 acc[3][NI][NJ]) {
  const int tid = threadIdx.x;
  const int lane = tid & 63, wv = tid >> 6;
  const int wm = wv & 1, wn = wv >> 1;
  const int q = lane >> 4, l15 = lane & 15;
  const int srow = tid >> 3, sc8 = tid & 7;   // 8 threads/row, 32 rows/pass
  for (int kt = 0; kt < 384; kt += 64) {
    __syncthreads();                                       // guard Os/Ms0 vs prev compute
    stage_tile<OF32, 64>(Op, o0, kt, Os, srow, sc8);       // outer: once per kt
    stage_tile<MF32, 128>(Mp, mb + 0, kt, Ms0, srow, sc8);
    __syncthreads();
    stage_tile<MF32, 128>(Mp, mb + 128, kt, Ms1, srow, sc8);
    comp_tile<MULTI_A, NI, NJ>(Os, Ms0, acc[0], wm, wn, q, l15);
    __syncthreads();                                       // Ms1 ready; all done w/ Ms0
    stage_tile<MF32, 128>(Mp, mb + 256, kt, Ms0, srow, sc8);
    comp_tile<MULTI_A, NI, NJ>(Os, Ms1, acc[1], wm, wn, q, l15);
    __syncthreads();                                       // Ms0 ready; all done w/ Ms1
    comp_tile<MULTI_A, NI, NJ>(Os, Ms0, acc[2], wm, wn, q, l15);
  }
}

// coalesced tile store: S[64][TS] bf16 -> dst rows (row stride 384 u16)
__device__ __forceinline__ void tile_store64(const u16* S, u16* dst, int m0) {
  const int tid = threadIdx.x;
  const int col = (tid & 31) * 4, rowo = tid >> 5;   // 0..7
  #pragma unroll
  for (int rr = 0; rr < 8; ++rr) {
    int row = rr * 8 + rowo;
    *(u64*)(dst + (size_t)(m0 + row) * 384 + col) = *(const u64*)&S[row * TS + col];
  }
}

// GEMM1: h(bf16) @ lin_w^T(fp32) + lin_b -> xx (cols<384), z (cols>=384), bf16 channel-last
__global__ __launch_bounds__(256) void k_gemm_lin(const u16* __restrict__ A,
                                                  const float* __restrict__ Bw,
                                                  const float* __restrict__ bias,
                                                  u16* __restrict__ xx, u16* __restrict__ z) {
  __shared__ __align__(16) u16 S[SH_U16];
  u16* Os = S; u16* Ms0 = S + 64 * LDA; u16* Ms1 = Ms0 + 128 * LDA;
  floatx4 acc[3][2][4];
  { floatx4 zv = {0.f, 0.f, 0.f, 0.f};
    #pragma unroll
    for (int t = 0; t < 3; ++t)
      #pragma unroll
      for (int i = 0; i < 2; ++i)
        #pragma unroll
        for (int j = 0; j < 4; ++j) acc[t][i][j] = zv; }
  const int tid = threadIdx.x;
  const int lane = tid & 63, wv = tid >> 6;
  const int wm = wv & 1, wn = wv >> 1, q = lane >> 4, l15 = lane & 15;
  const int nb = blockIdx.x * 384, m0 = blockIdx.y * 64;   // x-consecutive share A-tile
  gemm3<false, true, false, 2, 4>(A, Bw, m0, nb, Os, Ms0, Ms1, acc);
  #pragma unroll
  for (int t = 0; t < 3; ++t) {
    int n0 = nb + t * 128;
    __syncthreads();
    #pragma unroll
    for (int i = 0; i < 2; ++i)
      #pragma unroll
      for (int j = 0; j < 4; ++j) {
        int nl = wn * 64 + j * 16 + l15;
        float bb = bias[n0 + nl];
        #pragma unroll
        for (int r = 0; r < 4; ++r) {
          int ml = wm * 32 + i * 16 + q * 4 + r;
          S[ml * TS + nl] = f2bf(acc[t][i][j][r] + bb);
        }
      }
    __syncthreads();
    u16* dst = (n0 < 384) ? (xx + n0) : (z + (n0 - 384));
    tile_store64(S, dst, m0);
  }
}

// GEMM2: freq_embed(fp32) @ tok_w^T(fp32) + tok_b -> gelu -> wave gain g (bf16)
__global__ __launch_bounds__(256) void k_gemm_tok(const float* __restrict__ A,
                                                  const float* __restrict__ Bw,
                                                  const float* __restrict__ bias,
                                                  const float* __restrict__ cs,
                                                  const float* __restrict__ al,
                                                  u16* __restrict__ g) {
  __shared__ __align__(16) u16 S[SH_U16];
  u16* Os = S; u16* Ms0 = S + 64 * LDA; u16* Ms1 = Ms0 + 128 * LDA;
  floatx4 acc[3][2][4];
  { floatx4 zv = {0.f, 0.f, 0.f, 0.f};
    #pragma unroll
    for (int t = 0; t < 3; ++t)
      #pragma unroll
      for (int i = 0; i < 2; ++i)
        #pragma unroll
        for (int j = 0; j < 4; ++j) acc[t][i][j] = zv; }
  const int tid = threadIdx.x;
  const int lane = tid & 63, wv = tid >> 6;
  const int wm = wv & 1, wn = wv >> 1, q = lane >> 4, l15 = lane & 15;
  const int m0 = blockIdx.x * 64;
  gemm3<true, true, false, 2, 4>(A, Bw, m0, 0, Os, Ms0, Ms1, acc);
  const float c0 = cs[0], a0 = al[0];
  const float sc = (1.0f / (c0 + 1e-8f)) * (1.0f + 0.5f * a0);
  #pragma unroll
  for (int t = 0; t < 3; ++t) {
    __syncthreads();
    #pragma unroll
    for (int i = 0; i < 2; ++i)
      #pragma unroll
      for (int j = 0; j < 4; ++j) {
        int nl = wn * 64 + j * 16 + l15;
        float bb = bias[t * 128 + nl];
        #pragma unroll
        for (int r = 0; r < 4; ++r) {
          int ml = wm * 32 + i * 16 + q * 4 + r;
          float v = acc[t][i][j][r] + bb;
          float tt = 0.5f * v * (1.0f + erff(v * 0.7071067811865476f));  // exact gelu
          float ct = c0 * tt;
          S[ml * TS + nl] = f2bf(cosf(ct) + sinf(ct) * sc);
        }
      }
    __syncthreads();
    tile_store64(S, g + t * 128, m0);
  }
}

// GEMM3: out_w(fp32, M=channel, multi) x A3(bf16, N=pixel, outer) -> d_out fp32 + out_b
__global__ __launch_bounds__(256) void k_gemm_out(const float* __restrict__ A,
                                                  const u16* __restrict__ Bp,
                                                  const float* __restrict__ bias,
                                                  float* __restrict__ outp) {
  __shared__ __align__(16) u16 S[SH_U16];
  u16* Os = S; u16* Ms0 = S + 64 * LDA; u16* Ms1 = Ms0 + 128 * LDA;
  floatx4 acc[3][4][2];
  { floatx4 zv = {0.f, 0.f, 0.f, 0.f};
    #pragma unroll
    for (int t = 0; t < 3; ++t)
      #pragma unroll
      for (int i = 0; i < 4; ++i)
        #pragma unroll
        for (int j = 0; j < 2; ++j) acc[t][i][j] = zv; }
  const int tid = threadIdx.x;
  const int lane = tid & 63, wv = tid >> 6;
  const int wm = wv & 1, wn = wv >> 1, q = lane >> 4, l15 = lane & 15;
  const int n0 = blockIdx.x * 64;                 // pixel slice (outer, read once)
  gemm3<false, true, true, 4, 2>(Bp, A, n0, 0, Os, Ms0, Ms1, acc);
  #pragma unroll
  for (int t = 0; t < 3; ++t)
    #pragma unroll
    for (int i = 0; i < 4; ++i)
      #pragma unroll
      for (int j = 0; j < 2; ++j) {
        int pix = n0 + wn * 32 + j * 16 + l15;    // pixel index
        int b = pix / 3136, p = pix - b * 3136;
        #pragma unroll
        for (int r = 0; r < 4; ++r) {
          int m = t * 128 + wm * 64 + i * 16 + q * 4 + r;   // channel
          outp[((size_t)b * 384 + m) * 3136 + p] = acc[t][i][j][r] + bias[m];
        }
      }
}

// ---------------- DCT chain (fp32 math, bf16 storage, in-place) ----------------
// xx[b,h,w,c] -> u1[b,n,w,c] = sum_h Wd[n,h]*xx  (in-place)
__global__ __launch_bounds__(256) void k_dct_h(u16* __restrict__ xx,
                                               const float* __restrict__ Wd) {
  __shared__ float Xs[56 * 128];
  __shared__ float Ws[3136];
  const int w = blockIdx.x, cb = blockIdx.y * 128, b = blockIdx.z;
  const int tid = threadIdx.x;
  for (int i = tid; i < 3136; i += 256) Ws[i] = Wd[i];
  for (int i = tid; i < 56 * 64; i += 256) {
    int h = i >> 6, cu = i & 63;
    unsigned int p = *(const unsigned int*)(xx + ((size_t)(b * 56 + h) * 56 + w) * 384 + cb + cu * 2);
    bfp(p, Xs[h * 128 + cu * 2], Xs[h * 128 + cu * 2 + 1]);
  }
  __syncthreads();
  const int lane = tid & 63, wv = tid >> 6;
  float a0[14], a1[14];
  #pragma unroll
  for (int k = 0; k < 14; ++k) { a0[k] = 0.f; a1[k] = 0.f; }
  for (int h = 0; h < 56; ++h) {
    float x0 = Xs[h * 128 + 2 * lane];
    float x1 = Xs[h * 128 + 2 * lane + 1];
    #pragma unroll
    for (int k = 0; k < 14; ++k) {
      float wn = Ws[(wv + 4 * k) * 56 + h];
      a0[k] += wn * x0; a1[k] += wn * x1;
    }
  }
  #pragma unroll
  for (int k = 0; k < 14; ++k) {
    int n = wv + 4 * k;
    *(unsigned int*)(xx + ((size_t)(b * 56 + n) * 56 + w) * 384 + cb + 2 * lane) = packbf(a0[k], a1[k]);
  }
}

// fused: V = Wd @ u1[b,n] (over w); V *= g; y1[b,n] = Wd^T @ V (over m). In-place on u1.
__global__ __launch_bounds__(256) void k_mid(u16* __restrict__ u1,
                                             const u16* __restrict__ g,
                                             const float* __restrict__ Wd) {
  __shared__ float Us[56 * 64];
  __shared__ float Vs[56 * 64];
  __shared__ float Ws[3136];
  const int n = blockIdx.x, cb = blockIdx.y * 64, b = blockIdx.z;
  const int tid = threadIdx.x;
  for (int i = tid; i < 3136; i += 256) Ws[i] = Wd[i];
  for (int i = tid; i < 56 * 32; i += 256) {
    int ww = i >> 5, cu = i & 31;
    unsigned int p = *(const unsigned int*)(u1 + ((size_t)(b * 56 + n) * 56 + ww) * 384 + cb + cu * 2);
    bfp(p, Us[ww * 64 + cu * 2], Us[ww * 64 + cu * 2 + 1]);
  }
  __syncthreads();
  const int lane = tid & 63, wv = tid >> 6;
  {
    float a[14];
    #pragma unroll
    for (int k = 0; k < 14; ++k) a[k] = 0.f;
    for (int ww = 0; ww < 56; ++ww) {
      float xv = Us[ww * 64 + lane];
      #pragma unroll
      for (int k = 0; k < 14; ++k)
        a[k] += Ws[(wv + 4 * k) * 56 + ww] * xv;
    }
    #pragma unroll
    for (int k = 0; k < 14; ++k) Vs[(wv + 4 * k) * 64 + lane] = a[k];
  }
  __syncthreads();
  for (int i = tid; i < 56 * 32; i += 256) {
    int m = i >> 5, cu = i & 31;
    unsigned int p = *(const unsigned int*)(g + ((size_t)(b * 56 + n) * 56 + m) * 384 + cb + cu * 2);
    float g0, g1; bfp(p, g0, g1);
    Vs[m * 64 + cu * 2]     *= g0;
    Vs[m * 64 + cu * 2 + 1] *= g1;
  }
  __syncthreads();
  {
    float a[14];
    #pragma unroll
    for (int k = 0; k < 14; ++k) a[k] = 0.f;
    for (int m = 0; m < 56; ++m) {
      float xv = Vs[m * 64 + lane];
      #pragma unroll
      for (int k = 0; k < 14; ++k)
        a[k] += Ws[m * 56 + (wv + 4 * k)] * xv;   // Wd[m, yy]
    }
    #pragma unroll
    for (int k = 0; k < 14; ++k) {
      int yy = wv + 4 * k;
      u1[((size_t)(b * 56 + n) * 56 + yy) * 384 + cb + lane] = f2bf(a[k]);
    }
  }
}

// y1[b,n,yy,c] -> y2[b,x,yy,c] = sum_n Wd[n,x]*y1  (in-place)
__global__ __launch_bounds__(256) void k_idct_h(u16* __restrict__ y1,
                                                const float* __restrict__ Wd) {
  __shared__ float Ys[56 * 128];
  __shared__ float Ws[3136];
  const int yy = blockIdx.x, cb = blockIdx.y * 128, b = blockIdx.z;
  const int tid = threadIdx.x;
  for (int i = tid; i < 3136; i += 256) Ws[i] = Wd[i];
  for (int i = tid; i < 56 * 64; i += 256) {
    int nn = i >> 6, cu = i & 63;
    unsigned int p = *(const unsigned int*)(y1 + ((size_t)(b * 56 + nn) * 56 + yy) * 384 + cb + cu * 2);
    bfp(p, Ys[nn * 128 + cu * 2], Ys[nn * 128 + cu * 2 + 1]);
  }
  __syncthreads();
  const int lane = tid & 63, wv = tid >> 6;
  float a0[14], a1[14];
  #pragma unroll
  for (int k = 0; k < 14; ++k) { a0[k] = 0.f; a1[k] = 0.f; }
  for (int nn = 0; nn < 56; ++nn) {
    float x0 = Ys[nn * 128 + 2 * lane];
    float x1 = Ys[nn * 128 + 2 * lane + 1];
    #pragma unroll
    for (int k = 0; k < 14; ++k) {
      float wn = Ws[nn * 56 + (wv + 4 * k)];   // Wd[n, x]
      a0[k] += wn * x0; a1[k] += wn * x1;
    }
  }
  #pragma unroll
  for (int k = 0; k < 14; ++k) {
    int x = wv + 4 * k;
    *(unsigned int*)(y1 + ((size_t)(b * 56 + x) * 56 + yy) * 384 + cb + 2 * lane) = packbf(a0[k], a1[k]);
  }
}

// ---------------- LayerNorm + SiLU gate -> bf16 A3 (in-place over y2) ----------------
__global__ __launch_bounds__(256) void k_ln(u16* __restrict__ y2,
                                            const u16* __restrict__ z,
                                            const float* __restrict__ lgm,
                                            const float* __restrict__ lbt) {
  const int t = blockIdx.x * 4 + (threadIdx.x >> 6);
  const int lane = threadIdx.x & 63;
  u16* yr = y2 + (size_t)t * 384;
  const u16* zr = z + (size_t)t * 384;
  float v[6]; float s = 0.f, s2 = 0.f;
  #pragma unroll
  for (int k = 0; k < 3; ++k) {
    unsigned int p = *(const unsigned int*)(yr + 2 * lane + 128 * k);
    float f0, f1; bfp(p, f0, f1);
    v[2 * k] = f0; v[2 * k + 1] = f1;
    s += f0 + f1; s2 += f0 * f0 + f1 * f1;
  }
  #pragma unroll
  for (int off = 32; off >= 1; off >>= 1) {
    s  += __shfl_xor(s, off, 64);
    s2 += __shfl_xor(s2, off, 64);
  }
  const float mu  = s * (1.0f / 384.0f);
  const float var = s2 * (1.0f / 384.0f) - mu * mu;
  const float inv = rsqrtf(var + 1e-5f);
  #pragma unroll
  for (int k = 0; k < 3; ++k) {
    int c = 2 * lane + 128 * k;
    float z0, z1;
    bfp(*(const unsigned int*)(zr + c), z0, z1);
    float yn0 = (v[2 * k]     - mu) * inv * lgm[c]     + lbt[c];
    float yn1 = (v[2 * k + 1] - mu) * inv * lgm[c + 1] + lbt[c + 1];
    float ga0 = z0 / (1.0f + expf(-z0));
    float ga1 = z1 / (1.0f + expf(-z1));
    *(unsigned int*)(yr + c) = packbf(yn0 * ga0, yn1 * ga1);
  }
}

// ---------------- launch ----------------
extern "C" void kernel_launch(void* const* d_in, const int* in_sizes, int n_in,
                              void* d_out, int out_size, void* d_ws, size_t ws_size,
                              hipStream_t stream) {
  const float* x     = (const float*)d_in[0];
  const float* fe    = (const float*)d_in[1];
  const float* dw_w  = (const float*)d_in[2];
  const float* dw_b  = (const float*)d_in[3];
  const float* lin_w = (const float*)d_in[4];
  const float* lin_b = (const float*)d_in[5];
  const float* tok_w = (const float*)d_in[6];
  const float* tok_b = (const float*)d_in[7];
  const float* ln_g  = (const float*)d_in[8];
  const float* ln_b  = (const float*)d_in[9];
  const float* out_w = (const float*)d_in[10];
  const float* out_b = (const float*)d_in[11];
  const float* cs    = (const float*)d_in[12];
  const float* al    = (const float*)d_in[13];
  float* outp = (float*)d_out;
  char* ws = (char*)d_ws;

  float* Wd = (float*)(ws + 0);                        // 12,544 B
  u16* SA = (u16*)(ws + 16384);                        // h, then g
  u16* SB = (u16*)(ws + 16384 + 38535168);             // xx -> u1 -> y1 -> y2 -> A3 (in-place chain)
  u16* SC = (u16*)(ws + 16384 + 2 * (size_t)38535168); // z

  k_dctmat<<<dim3(13), dim3(256), 0, stream>>>(Wd);
  k_conv<<<dim3(56, 6, 16), dim3(256), 0, stream>>>(x, dw_w, dw_b, SA);          // h in SA
  k_gemm_lin<<<dim3(2, 784), dim3(256), 0, stream>>>(SA, lin_w, lin_b, SB, SC);  // xx in SB, z in SC
  k_gemm_tok<<<dim3(784), dim3(256), 0, stream>>>(fe, tok_w, tok_b, cs, al, SA); // g in SA
  k_dct_h<<<dim3(56, 3, 16), dim3(256), 0, stream>>>(SB, Wd);                    // xx -> u1
  k_mid<<<dim3(56, 6, 16), dim3(256), 0, stream>>>(SB, SA, Wd);                  // u1,g -> y1
  k_idct_h<<<dim3(56, 3, 16), dim3(256), 0, stream>>>(SB, Wd);                   // y1 -> y2
  k_ln<<<dim3(12544), dim3(256), 0, stream>>>(SB, SC, ln_g, ln_b);               // y2,z -> A3
  k_gemm_out<<<dim3(784), dim3(256), 0, stream>>>(out_w, SB, out_b, outp);
}

// Round 2
// 866.386 us; speedup vs baseline: 1.2360x; 1.2360x over previous
//
#include <hip/hip_runtime.h>
#include <cstdint>
#include <cstddef>

typedef __attribute__((ext_vector_type(8))) short short8;
typedef __attribute__((ext_vector_type(4))) float floatx4;
typedef unsigned short u16;
typedef unsigned long long u64;

__device__ __forceinline__ float bf2f(u16 u) {
  union { unsigned int i; float f; } v; v.i = ((unsigned int)u) << 16; return v.f;
}
__device__ __forceinline__ u16 f2bf(float f) {
  union { float f; unsigned int u; } v; v.f = f;
  return (u16)((v.u + 0x7fffu + ((v.u >> 16) & 1u)) >> 16);
}
__device__ __forceinline__ void bfp(unsigned int p, float& x, float& y) {
  union { unsigned int i; float f; } a, b;
  a.i = p << 16; b.i = p & 0xffff0000u;
  x = a.f; y = b.f;
}
__device__ __forceinline__ unsigned int packbf(float a, float b) {
  return (unsigned int)f2bf(a) | ((unsigned int)f2bf(b) << 16);
}
__device__ __forceinline__ u64 pack4(float a, float b, float c, float d) {
  return (u64)f2bf(a) | ((u64)f2bf(b) << 16) | ((u64)f2bf(c) << 32) | ((u64)f2bf(d) << 48);
}

typedef __attribute__((address_space(1))) const unsigned int gu32;
typedef __attribute__((address_space(3))) unsigned int lu32;
__device__ __forceinline__ void gl2lds16(const void* g, void* l) {
  __builtin_amdgcn_global_load_lds((gu32*)g, (lu32*)l, 16, 0, 0);
}

// XCD-chunked swizzle: consecutive work-ids land on the SAME XCD L2.
__device__ __forceinline__ int xcd_swz(int id, int nwg) {
  int cpx = nwg >> 3;                 // nwg % 8 == 0 for all our grids
  return (id & 7) * cpx + (id >> 3);
}

// ---------------- DCT-II orthonormal 56x56 matrix (fp32) ----------------
__global__ __launch_bounds__(256) void k_dctmat(float* __restrict__ Wd) {
  int i = blockIdx.x * 256 + threadIdx.x;
  if (i < 56 * 56) {
    int n = i / 56, x = i - n * 56;
    float v = cosf(3.14159265358979323846f * (float)n * ((float)x + 0.5f) / 56.0f)
              * 0.1889822365046136f;            // sqrt(2/56)
    if (n == 0) v *= 0.7071067811865476f;
    Wd[i] = v;
  }
}

// ---------------- weights fp32 -> bf16 (lin_w | tok_w | out_w) ----------------
__global__ __launch_bounds__(256) void k_castw(const float* __restrict__ a,
                                               const float* __restrict__ b,
                                               const float* __restrict__ c,
                                               u16* __restrict__ o) {
  int i = blockIdx.x * 256 + threadIdx.x;   // float4 index, 147456 total
  const float* src; int off;
  if (i < 73728)        { src = a; off = 0; }
  else if (i < 110592)  { src = b; off = 294912; i -= 73728; }
  else                  { src = c; off = 442368; i -= 110592; }
  float4 v = ((const float4*)src)[i];
  *(u64*)&o[off + i * 4] = pack4(v.x, v.y, v.z, v.w);
}

// ---------------- depthwise conv 3x3, NCHW fp32 -> channel-last bf16 ----------------
__global__ __launch_bounds__(256) void k_conv(const float* __restrict__ x,
                                              const float* __restrict__ w9,
                                              const float* __restrict__ b1,
                                              u16* __restrict__ hbf) {
  __shared__ float xs[64 * 177];  // [c][3 rows][59 cols], col 0 <-> gx=-1
  const int y = blockIdx.x, c0 = blockIdx.y * 64, b = blockIdx.z;
  const int tid = threadIdx.x, cl = tid & 63, wv = tid >> 6;
  float wr[9];
  #pragma unroll
  for (int k = 0; k < 9; ++k) wr[k] = w9[(c0 + cl) * 9 + k];
  const float br = b1[c0 + cl];
  for (int it = 0; it < 48; ++it) {
    int combo = it * 4 + wv;             // 0..191 -> (c, r)
    int c = combo / 3, r = combo - c * 3;
    int col = tid & 63;
    if (col < 58) {
      int gy = y + r - 1, gx = col - 1;
      float v = 0.f;
      if (gy >= 0 && gy < 56 && gx >= 0 && gx < 56)
        v = x[(((size_t)b * 384 + c0 + c) * 56 + gy) * 56 + gx];
      xs[c * 177 + r * 59 + col] = v;
    }
  }
  __syncthreads();
  for (int it = 0; it < 14; ++it) {
    int px = it * 4 + wv;
    float a = br;
    #pragma unroll
    for (int dy = 0; dy < 3; ++dy)
      #pragma unroll
      for (int dx = 0; dx < 3; ++dx)
        a += wr[dy * 3 + dx] * xs[cl * 177 + dy * 59 + px + dx];
    hbf[((size_t)b * 3136 + y * 56 + px) * 384 + c0 + cl] = f2bf(a);
  }
}

// ---------------- MFMA GEMM core, 128x128 tile, K=384, 2 barriers/K-step ----------------
// LDS linear (LDK=64) for global_load_lds; T2 XOR swizzle achieved by permuting the
// per-lane GLOBAL source column (DMA) / LDS slot (reg-stage); frag reads apply same XOR.
#define LDK 64
#define TS 132
#define S_U16 16896   // max(2*128*64, 128*132) -> 33792 B

// bf16 source, direct-to-LDS DMA. LDS dest per lane = wave base + lane*16 (linear).
__device__ __forceinline__ void stage_dma(const u16* __restrict__ src, int base, int kt,
                                          u16* __restrict__ buf, int tid) {
  const int r0 = tid >> 3, c8 = tid & 7;
  const int scol = (c8 ^ (r0 & 7)) << 3;     // source-permute => swizzled LDS content
  #pragma unroll
  for (int p = 0; p < 4; ++p) {
    int row = p * 32 + r0;
    gl2lds16(src + (size_t)(base + row) * 384 + kt + scol, &buf[row * LDK + (c8 << 3)]);
  }
}

// fp32 source, register staging with bf16 pack; write the swizzled LDS slot directly.
__device__ __forceinline__ void stage_f32(const float* __restrict__ src, int base, int kt,
                                          u16* __restrict__ buf, int tid) {
  const int r0 = tid >> 3, c8 = tid & 7;
  const int dcol = (c8 ^ (r0 & 7)) << 3;
  #pragma unroll
  for (int p = 0; p < 4; ++p) {
    int row = p * 32 + r0;
    const float4* s = (const float4*)(src + (size_t)(base + row) * 384 + kt + (c8 << 3));
    float4 v0 = s[0], v1 = s[1];
    union { short8 s8; u64 q[2]; } t;
    t.q[0] = pack4(v0.x, v0.y, v0.z, v0.w);
    t.q[1] = pack4(v1.x, v1.y, v1.z, v1.w);
    *(short8*)&buf[row * LDK + dcol] = t.s8;
  }
}

__device__ __forceinline__ short8 frag_read(const u16* buf, int r, int u) {
  return *(const short8*)&buf[r * LDK + (((u ^ (r & 7)) << 3))];
}

template<bool AF32>
__device__ __forceinline__ void gemm_core(const void* __restrict__ Ap,
                                          const u16* __restrict__ Bp,
                                          int m0, int n0, u16* As, u16* Bs,
                                          floatx4 acc[4][4]) {
  const int tid = threadIdx.x;
  const int lane = tid & 63, wv = tid >> 6;
  const int wm = wv & 1, wn = wv >> 1;
  const int q = lane >> 4, l15 = lane & 15;
  for (int kt = 0; kt < 384; kt += 64) {
    __syncthreads();                       // prev compute done reading LDS
    stage_dma(Bp, n0, kt, Bs, tid);        // DMA first: in flight during A pack
    if constexpr (AF32) stage_f32((const float*)Ap, m0, kt, As, tid);
    else                stage_dma((const u16*)Ap, m0, kt, As, tid);
    __syncthreads();                       // drains vmcnt+lgkmcnt: tiles ready
    #pragma unroll
    for (int kc = 0; kc < 64; kc += 32) {
      short8 af[4], bf[4];
      #pragma unroll
      for (int i = 0; i < 4; ++i) {
        af[i] = frag_read(As, wm * 64 + i * 16 + l15, (kc >> 3) + q);
        bf[i] = frag_read(Bs, wn * 64 + i * 16 + l15, (kc >> 3) + q);
      }
      #pragma unroll
      for (int i = 0; i < 4; ++i)
        #pragma unroll
        for (int j = 0; j < 4; ++j)
          acc[i][j] = __builtin_amdgcn_mfma_f32_16x16x32_bf16(af[i], bf[j], acc[i][j], 0, 0, 0);
    }
  }
}

#define GEMM_PROLOGUE() \
  __shared__ __align__(16) u16 S[S_U16]; \
  u16* As = S; u16* Bs = S + 128 * LDK; \
  floatx4 acc[4][4]; \
  { floatx4 zv = {0.f, 0.f, 0.f, 0.f}; \
    _Pragma("unroll") for (int i = 0; i < 4; ++i) \
      _Pragma("unroll") for (int j = 0; j < 4; ++j) acc[i][j] = zv; } \
  const int tid = threadIdx.x; \
  const int lane = tid & 63, wv = tid >> 6; \
  const int wm = wv & 1, wn = wv >> 1, q = lane >> 4, l15 = lane & 15; \
  (void)lane;

// coalesced tile store: S[128][TS] bf16 -> dst rows (row stride 384 u16)
__device__ __forceinline__ void tile_store(const u16* S, u16* dst, int m0) {
  const int tid = threadIdx.x;
  const int col = (tid & 31) * 4, rowo = tid >> 5;
  #pragma unroll
  for (int rr = 0; rr < 16; ++rr) {
    int row = rr * 8 + rowo;
    *(u64*)(dst + (size_t)(m0 + row) * 384 + col) = *(const u64*)&S[row * TS + col];
  }
}

// GEMM1: h(bf16) @ lin_w_bf^T + lin_b -> xx (n<384), z (n>=384), bf16 channel-last
__global__ __launch_bounds__(256) void k_gemm_lin(const u16* __restrict__ A,
                                                  const u16* __restrict__ Bw,
                                                  const float* __restrict__ bias,
                                                  u16* __restrict__ xx, u16* __restrict__ z) {
  GEMM_PROLOGUE();
  const int id = xcd_swz(blockIdx.x, 2352);
  const int n0 = (id % 6) * 128, m0 = (id / 6) * 128;   // same-XCD ids share A-tile
  gemm_core<false>(A, Bw, m0, n0, As, Bs, acc);
  __syncthreads();
  #pragma unroll
  for (int i = 0; i < 4; ++i)
    #pragma unroll
    for (int j = 0; j < 4; ++j) {
      int nl = wn * 64 + j * 16 + l15;
      float bb = bias[n0 + nl];
      #pragma unroll
      for (int r = 0; r < 4; ++r) {
        int ml = wm * 64 + i * 16 + q * 4 + r;
        S[ml * TS + nl] = f2bf(acc[i][j][r] + bb);
      }
    }
  __syncthreads();
  u16* dst = (n0 < 384) ? (xx + n0) : (z + (n0 - 384));
  tile_store(S, dst, m0);
}

// GEMM2: freq_embed(fp32) @ tok_w_bf^T + tok_b -> gelu -> wave gain g (bf16)
__global__ __launch_bounds__(256) void k_gemm_tok(const float* __restrict__ A,
                                                  const u16* __restrict__ Bw,
                                                  const float* __restrict__ bias,
                                                  const float* __restrict__ cs,
                                                  const float* __restrict__ al,
                                                  u16* __restrict__ g) {
  GEMM_PROLOGUE();
  const int id = xcd_swz(blockIdx.x, 1176);
  const int n0 = (id % 3) * 128, m0 = (id / 3) * 128;   // same-XCD ids share A-tile
  gemm_core<true>(A, Bw, m0, n0, As, Bs, acc);
  const float c0 = cs[0], a0 = al[0];
  const float sc = (1.0f / (c0 + 1e-8f)) * (1.0f + 0.5f * a0);
  __syncthreads();
  #pragma unroll
  for (int i = 0; i < 4; ++i)
    #pragma unroll
    for (int j = 0; j < 4; ++j) {
      int nl = wn * 64 + j * 16 + l15;
      float bb = bias[n0 + nl];
      #pragma unroll
      for (int r = 0; r < 4; ++r) {
        int ml = wm * 64 + i * 16 + q * 4 + r;
        float v = acc[i][j][r] + bb;
        float t = 0.5f * v * (1.0f + erff(v * 0.7071067811865476f));  // exact gelu
        float ct = c0 * t;
        S[ml * TS + nl] = f2bf(cosf(ct) + sinf(ct) * sc);
      }
    }
  __syncthreads();
  tile_store(S, g + n0, m0);
}

// GEMM3: out_w_bf(M=channel) x A3(bf16, N=pixel) -> d_out[b,c,h,w] fp32 + out_b
__global__ __launch_bounds__(256) void k_gemm_out(const u16* __restrict__ A,
                                                  const u16* __restrict__ Bp,
                                                  const float* __restrict__ bias,
                                                  float* __restrict__ outp) {
  GEMM_PROLOGUE();
  const int id = xcd_swz(blockIdx.x, 1176);
  const int m0 = (id % 3) * 128, n0 = (id / 3) * 128;   // same-XCD ids share B-tile (A3)
  gemm_core<false>(A, Bp, m0, n0, As, Bs, acc);
  #pragma unroll
  for (int i = 0; i < 4; ++i)
    #pragma unroll
    for (int j = 0; j < 4; ++j) {
      int t = n0 + wn * 64 + j * 16 + l15;      // pixel index
      int b = t / 3136, p = t - b * 3136;
      #pragma unroll
      for (int r = 0; r < 4; ++r) {
        int m = m0 + wm * 64 + i * 16 + q * 4 + r;   // channel
        outp[((size_t)b * 384 + m) * 3136 + p] = acc[i][j][r] + bias[m];
      }
    }
}

// ---------------- DCT chain (fp32 math, bf16 storage, in-place) ----------------
// xx[b,h,w,c] -> u1[b,n,w,c] = sum_h Wd[n,h]*xx  (in-place)
__global__ __launch_bounds__(256) void k_dct_h(u16* __restrict__ xx,
                                               const float* __restrict__ Wd) {
  __shared__ float Xs[56 * 128];
  __shared__ float Ws[3136];
  const int w = blockIdx.x, cb = blockIdx.y * 128, b = blockIdx.z;
  const int tid = threadIdx.x;
  for (int i = tid; i < 3136; i += 256) Ws[i] = Wd[i];
  for (int i = tid; i < 56 * 64; i += 256) {
    int h = i >> 6, cu = i & 63;
    unsigned int p = *(const unsigned int*)(xx + ((size_t)(b * 56 + h) * 56 + w) * 384 + cb + cu * 2);
    bfp(p, Xs[h * 128 + cu * 2], Xs[h * 128 + cu * 2 + 1]);
  }
  __syncthreads();
  const int lane = tid & 63, wv = tid >> 6;
  float a0[14], a1[14];
  #pragma unroll
  for (int k = 0; k < 14; ++k) { a0[k] = 0.f; a1[k] = 0.f; }
  for (int h = 0; h < 56; ++h) {
    float x0 = Xs[h * 128 + 2 * lane];
    float x1 = Xs[h * 128 + 2 * lane + 1];
    #pragma unroll
    for (int k = 0; k < 14; ++k) {
      float wn = Ws[(wv + 4 * k) * 56 + h];
      a0[k] += wn * x0; a1[k] += wn * x1;
    }
  }
  #pragma unroll
  for (int k = 0; k < 14; ++k) {
    int n = wv + 4 * k;
    *(unsigned int*)(xx + ((size_t)(b * 56 + n) * 56 + w) * 384 + cb + 2 * lane) = packbf(a0[k], a1[k]);
  }
}

// fused: V = Wd @ u1[b,n] (over w); V *= g; y1[b,n] = Wd^T @ V (over m). In-place on u1.
__global__ __launch_bounds__(256) void k_mid(u16* __restrict__ u1,
                                             const u16* __restrict__ g,
                                             const float* __restrict__ Wd) {
  __shared__ float Us[56 * 64];
  __shared__ float Vs[56 * 64];
  __shared__ float Ws[3136];
  const int n = blockIdx.x, cb = blockIdx.y * 64, b = blockIdx.z;
  const int tid = threadIdx.x;
  for (int i = tid; i < 3136; i += 256) Ws[i] = Wd[i];
  for (int i = tid; i < 56 * 32; i += 256) {
    int ww = i >> 5, cu = i & 31;
    unsigned int p = *(const unsigned int*)(u1 + ((size_t)(b * 56 + n) * 56 + ww) * 384 + cb + cu * 2);
    bfp(p, Us[ww * 64 + cu * 2], Us[ww * 64 + cu * 2 + 1]);
  }
  __syncthreads();
  const int lane = tid & 63, wv = tid >> 6;
  {
    float a[14];
    #pragma unroll
    for (int k = 0; k < 14; ++k) a[k] = 0.f;
    for (int ww = 0; ww < 56; ++ww) {
      float xv = Us[ww * 64 + lane];
      #pragma unroll
      for (int k = 0; k < 14; ++k)
        a[k] += Ws[(wv + 4 * k) * 56 + ww] * xv;
    }
    #pragma unroll
    for (int k = 0; k < 14; ++k) Vs[(wv + 4 * k) * 64 + lane] = a[k];
  }
  __syncthreads();
  for (int i = tid; i < 56 * 32; i += 256) {
    int m = i >> 5, cu = i & 31;
    unsigned int p = *(const unsigned int*)(g + ((size_t)(b * 56 + n) * 56 + m) * 384 + cb + cu * 2);
    float g0, g1; bfp(p, g0, g1);
    Vs[m * 64 + cu * 2]     *= g0;
    Vs[m * 64 + cu * 2 + 1] *= g1;
  }
  __syncthreads();
  {
    float a[14];
    #pragma unroll
    for (int k = 0; k < 14; ++k) a[k] = 0.f;
    for (int m = 0; m < 56; ++m) {
      float xv = Vs[m * 64 + lane];
      #pragma unroll
      for (int k = 0; k < 14; ++k)
        a[k] += Ws[m * 56 + (wv + 4 * k)] * xv;   // Wd[m, yy]
    }
    #pragma unroll
    for (int k = 0; k < 14; ++k) {
      int yy = wv + 4 * k;
      u1[((size_t)(b * 56 + n) * 56 + yy) * 384 + cb + lane] = f2bf(a[k]);
    }
  }
}

// y1[b,n,yy,c] -> y2[b,x,yy,c] = sum_n Wd[n,x]*y1  (in-place)
__global__ __launch_bounds__(256) void k_idct_h(u16* __restrict__ y1,
                                                const float* __restrict__ Wd) {
  __shared__ float Ys[56 * 128];
  __shared__ float Ws[3136];
  const int yy = blockIdx.x, cb = blockIdx.y * 128, b = blockIdx.z;
  const int tid = threadIdx.x;
  for (int i = tid; i < 3136; i += 256) Ws[i] = Wd[i];
  for (int i = tid; i < 56 * 64; i += 256) {
    int nn = i >> 6, cu = i & 63;
    unsigned int p = *(const unsigned int*)(y1 + ((size_t)(b * 56 + nn) * 56 + yy) * 384 + cb + cu * 2);
    bfp(p, Ys[nn * 128 + cu * 2], Ys[nn * 128 + cu * 2 + 1]);
  }
  __syncthreads();
  const int lane = tid & 63, wv = tid >> 6;
  float a0[14], a1[14];
  #pragma unroll
  for (int k = 0; k < 14; ++k) { a0[k] = 0.f; a1[k] = 0.f; }
  for (int nn = 0; nn < 56; ++nn) {
    float x0 = Ys[nn * 128 + 2 * lane];
    float x1 = Ys[nn * 128 + 2 * lane + 1];
    #pragma unroll
    for (int k = 0; k < 14; ++k) {
      float wn = Ws[nn * 56 + (wv + 4 * k)];   // Wd[n, x]
      a0[k] += wn * x0; a1[k] += wn * x1;
    }
  }
  #pragma unroll
  for (int k = 0; k < 14; ++k) {
    int x = wv + 4 * k;
    *(unsigned int*)(y1 + ((size_t)(b * 56 + x) * 56 + yy) * 384 + cb + 2 * lane) = packbf(a0[k], a1[k]);
  }
}

// ---------------- LayerNorm + SiLU gate -> bf16 A3 (in-place over y2) ----------------
__global__ __launch_bounds__(256) void k_ln(u16* __restrict__ y2,
                                            const u16* __restrict__ z,
                                            const float* __restrict__ lgm,
                                            const float* __restrict__ lbt) {
  const int t = blockIdx.x * 4 + (threadIdx.x >> 6);
  const int lane = threadIdx.x & 63;
  u16* yr = y2 + (size_t)t * 384;
  const u16* zr = z + (size_t)t * 384;
  float v[6]; float s = 0.f, s2 = 0.f;
  #pragma unroll
  for (int k = 0; k < 3; ++k) {
    unsigned int p = *(const unsigned int*)(yr + 2 * lane + 128 * k);
    float f0, f1; bfp(p, f0, f1);
    v[2 * k] = f0; v[2 * k + 1] = f1;
    s += f0 + f1; s2 += f0 * f0 + f1 * f1;
  }
  #pragma unroll
  for (int off = 32; off >= 1; off >>= 1) {
    s  += __shfl_xor(s, off, 64);
    s2 += __shfl_xor(s2, off, 64);
  }
  const float mu  = s * (1.0f / 384.0f);
  const float var = s2 * (1.0f / 384.0f) - mu * mu;
  const float inv = rsqrtf(var + 1e-5f);
  #pragma unroll
  for (int k = 0; k < 3; ++k) {
    int c = 2 * lane + 128 * k;
    float z0, z1;
    bfp(*(const unsigned int*)(zr + c), z0, z1);
    float yn0 = (v[2 * k]     - mu) * inv * lgm[c]     + lbt[c];
    float yn1 = (v[2 * k + 1] - mu) * inv * lgm[c + 1] + lbt[c + 1];
    float ga0 = z0 / (1.0f + expf(-z0));
    float ga1 = z1 / (1.0f + expf(-z1));
    *(unsigned int*)(yr + c) = packbf(yn0 * ga0, yn1 * ga1);
  }
}

// ---------------- launch ----------------
extern "C" void kernel_launch(void* const* d_in, const int* in_sizes, int n_in,
                              void* d_out, int out_size, void* d_ws, size_t ws_size,
                              hipStream_t stream) {
  const float* x     = (const float*)d_in[0];
  const float* fe    = (const float*)d_in[1];
  const float* dw_w  = (const float*)d_in[2];
  const float* dw_b  = (const float*)d_in[3];
  const float* lin_w = (const float*)d_in[4];
  const float* lin_b = (const float*)d_in[5];
  const float* tok_w = (const float*)d_in[6];
  const float* tok_b = (const float*)d_in[7];
  const float* ln_g  = (const float*)d_in[8];
  const float* ln_b  = (const float*)d_in[9];
  const float* out_w = (const float*)d_in[10];
  const float* out_b = (const float*)d_in[11];
  const float* cs    = (const float*)d_in[12];
  const float* al    = (const float*)d_in[13];
  float* outp = (float*)d_out;
  char* ws = (char*)d_ws;

  float* Wd = (float*)(ws + 0);                        // 12,544 B (pad to 16 KiB)
  u16* SA = (u16*)(ws + 16384);                        // h, then g
  u16* SB = (u16*)(ws + 16384 + 38535168);             // xx -> u1 -> y1 -> y2 -> A3 (in-place chain)
  u16* SC = (u16*)(ws + 16384 + 2 * (size_t)38535168); // z
  u16* Wbf = (u16*)(ws + 16384 + 3 * (size_t)38535168);// lin_w|tok_w|out_w bf16 (1,179,648 B)

  k_dctmat<<<dim3(13), dim3(256), 0, stream>>>(Wd);
  k_castw<<<dim3(576), dim3(256), 0, stream>>>(lin_w, tok_w, out_w, Wbf);
  k_conv<<<dim3(56, 6, 16), dim3(256), 0, stream>>>(x, dw_w, dw_b, SA);            // h in SA
  k_gemm_lin<<<dim3(2352), dim3(256), 0, stream>>>(SA, Wbf, lin_b, SB, SC);        // xx in SB, z in SC
  k_gemm_tok<<<dim3(1176), dim3(256), 0, stream>>>(fe, Wbf + 294912, tok_b, cs, al, SA); // g in SA
  k_dct_h<<<dim3(56, 3, 16), dim3(256), 0, stream>>>(SB, Wd);                      // xx -> u1
  k_mid<<<dim3(56, 6, 16), dim3(256), 0, stream>>>(SB, SA, Wd);                    // u1,g -> y1
  k_idct_h<<<dim3(56, 3, 16), dim3(256), 0, stream>>>(SB, Wd);                     // y1 -> y2
  k_ln<<<dim3(12544), dim3(256), 0, stream>>>(SB, SC, ln_g, ln_b);                 // y2,z -> A3
  k_gemm_out<<<dim3(1176), dim3(256), 0, stream>>>(Wbf + 442368, SB, out_b, outp);
}

// Round 3
// 753.115 us; speedup vs baseline: 1.4219x; 1.1504x over previous
//
#include <hip/hip_runtime.h>
#include <cstdint>
#include <cstddef>

typedef __attribute__((ext_vector_type(8))) short short8;
typedef __attribute__((ext_vector_type(4))) float floatx4;
typedef unsigned short u16;
typedef unsigned long long u64;

__device__ __forceinline__ float bf2f(u16 u) {
  union { unsigned int i; float f; } v; v.i = ((unsigned int)u) << 16; return v.f;
}
__device__ __forceinline__ u16 f2bf(float f) {
  union { float f; unsigned int u; } v; v.f = f;
  return (u16)((v.u + 0x7fffu + ((v.u >> 16) & 1u)) >> 16);
}
__device__ __forceinline__ void bfp(unsigned int p, float& x, float& y) {
  union { unsigned int i; float f; } a, b;
  a.i = p << 16; b.i = p & 0xffff0000u;
  x = a.f; y = b.f;
}
__device__ __forceinline__ unsigned int packbf(float a, float b) {
  return (unsigned int)f2bf(a) | ((unsigned int)f2bf(b) << 16);
}
__device__ __forceinline__ u64 pack4(float a, float b, float c, float d) {
  return (u64)f2bf(a) | ((u64)f2bf(b) << 16) | ((u64)f2bf(c) << 32) | ((u64)f2bf(d) << 48);
}

typedef __attribute__((address_space(1))) const unsigned int gu32;
typedef __attribute__((address_space(3))) unsigned int lu32;
__device__ __forceinline__ void gl2lds16(const void* g, void* l) {
  __builtin_amdgcn_global_load_lds((gu32*)g, (lu32*)l, 16, 0, 0);
}

// XCD-chunked swizzle: consecutive work-ids land on the SAME XCD L2.
__device__ __forceinline__ int xcd_swz(int id, int nwg) {
  int cpx = nwg >> 3;                 // nwg % 8 == 0 for all our grids
  return (id & 7) * cpx + (id >> 3);
}

// exact-gelu via A&S 7.1.26 erf rational (|err| < 1.5e-7), one native exp
__device__ __forceinline__ float gelu_fast(float v) {
  float xg = v * 0.7071067811865476f;
  float ax = fabsf(xg);
  float tr = __builtin_amdgcn_rcpf(fmaf(0.3275911f, ax, 1.0f));
  float pl = tr * (0.254829592f + tr * (-0.284496736f + tr * (1.421413741f +
             tr * (-1.453152027f + tr * 1.061405429f))));
  float er = 1.0f - pl * __expf(-xg * xg);
  er = (xg < 0.f) ? -er : er;
  return 0.5f * v * (1.0f + er);
}

// ---------------- fused prep: fe fp32->bf16, weights fp32->bf16, DCT matrix ----------------
#define FE_F4 4816896    // 16*3136*384 / 4
#define W_F4  147456     // (2C*C + C*C + C*C) / 4 = 589824/4
__global__ __launch_bounds__(256) void k_prep(const float* __restrict__ fe,
                                              const float* __restrict__ lw,
                                              const float* __restrict__ tw,
                                              const float* __restrict__ ow,
                                              u16* __restrict__ febf,
                                              u16* __restrict__ wbf,
                                              float* __restrict__ Wd) {
  int gid = blockIdx.x * 256 + threadIdx.x;
  if (gid < FE_F4) {
    float4 v = ((const float4*)fe)[gid];
    *(u64*)&febf[gid * 4] = pack4(v.x, v.y, v.z, v.w);
    return;
  }
  gid -= FE_F4;
  if (gid < W_F4) {
    const float* src; int off; int i = gid;
    if (i < 73728)        { src = lw; off = 0; }
    else if (i < 110592)  { src = tw; off = 294912; i -= 73728; }
    else                  { src = ow; off = 442368; i -= 110592; }
    float4 v = ((const float4*)src)[i];
    *(u64*)&wbf[off + i * 4] = pack4(v.x, v.y, v.z, v.w);
    return;
  }
  gid -= W_F4;
  if (gid < 784) {
    #pragma unroll
    for (int j = 0; j < 4; ++j) {
      int i = gid * 4 + j;
      int n = i / 56, x = i - n * 56;
      float v = cosf(3.14159265358979323846f * (float)n * ((float)x + 0.5f) / 56.0f)
                * 0.1889822365046136f;            // sqrt(2/56)
      if (n == 0) v *= 0.7071067811865476f;
      Wd[i] = v;
    }
  }
}

// ---------------- depthwise conv 3x3, NCHW fp32 -> channel-last bf16 ----------------
__global__ __launch_bounds__(256) void k_conv(const float* __restrict__ x,
                                              const float* __restrict__ w9,
                                              const float* __restrict__ b1,
                                              u16* __restrict__ hbf) {
  __shared__ float xs[64 * 177];  // [c][3 rows][59 cols], col 0 <-> gx=-1
  const int y = blockIdx.x, c0 = blockIdx.y * 64, b = blockIdx.z;
  const int tid = threadIdx.x, cl = tid & 63, wv = tid >> 6;
  float wr[9];
  #pragma unroll
  for (int k = 0; k < 9; ++k) wr[k] = w9[(c0 + cl) * 9 + k];
  const float br = b1[c0 + cl];
  for (int it = 0; it < 48; ++it) {
    int combo = it * 4 + wv;             // 0..191 -> (c, r)
    int c = combo / 3, r = combo - c * 3;
    int col = tid & 63;
    if (col < 58) {
      int gy = y + r - 1, gx = col - 1;
      float v = 0.f;
      if (gy >= 0 && gy < 56 && gx >= 0 && gx < 56)
        v = x[(((size_t)b * 384 + c0 + c) * 56 + gy) * 56 + gx];
      xs[c * 177 + r * 59 + col] = v;
    }
  }
  __syncthreads();
  for (int it = 0; it < 14; ++it) {
    int px = it * 4 + wv;
    float a = br;
    #pragma unroll
    for (int dy = 0; dy < 3; ++dy)
      #pragma unroll
      for (int dx = 0; dx < 3; ++dx)
        a += wr[dy * 3 + dx] * xs[cl * 177 + dy * 59 + px + dx];
    hbf[((size_t)b * 3136 + y * 56 + px) * 384 + c0 + cl] = f2bf(a);
  }
}

// ---------------- MFMA GEMM core, 128x128 tile, K=384, 2 barriers/K-step ----------------
#define LDK 64
#define TS 132
#define S_U16 16896   // max(2*128*64, 128*132) -> 33792 B

// bf16 source, direct-to-LDS DMA; XOR-permuted GLOBAL column => swizzled LDS content.
__device__ __forceinline__ void stage_dma(const u16* __restrict__ src, int base, int kt,
                                          u16* __restrict__ buf, int tid) {
  const int r0 = tid >> 3, c8 = tid & 7;
  const int scol = (c8 ^ (r0 & 7)) << 3;
  #pragma unroll
  for (int p = 0; p < 4; ++p) {
    int row = p * 32 + r0;
    gl2lds16(src + (size_t)(base + row) * 384 + kt + scol, &buf[row * LDK + (c8 << 3)]);
  }
}

__device__ __forceinline__ short8 frag_read(const u16* buf, int r, int u) {
  return *(const short8*)&buf[r * LDK + (((u ^ (r & 7)) << 3))];
}

__device__ __forceinline__ void gemm_core(const u16* __restrict__ Ap,
                                          const u16* __restrict__ Bp,
                                          int m0, int n0, u16* As, u16* Bs,
                                          floatx4 acc[4][4]) {
  const int tid = threadIdx.x;
  const int lane = tid & 63, wv = tid >> 6;
  const int wm = wv & 1, wn = wv >> 1;
  const int q = lane >> 4, l15 = lane & 15;
  for (int kt = 0; kt < 384; kt += 64) {
    __syncthreads();                       // prev compute done reading LDS
    stage_dma(Bp, n0, kt, Bs, tid);
    stage_dma(Ap, m0, kt, As, tid);
    __syncthreads();                       // drains vmcnt+lgkmcnt: tiles ready
    #pragma unroll
    for (int kc = 0; kc < 64; kc += 32) {
      short8 af[4], bf[4];
      #pragma unroll
      for (int i = 0; i < 4; ++i) {
        af[i] = frag_read(As, wm * 64 + i * 16 + l15, (kc >> 3) + q);
        bf[i] = frag_read(Bs, wn * 64 + i * 16 + l15, (kc >> 3) + q);
      }
      #pragma unroll
      for (int i = 0; i < 4; ++i)
        #pragma unroll
        for (int j = 0; j < 4; ++j)
          acc[i][j] = __builtin_amdgcn_mfma_f32_16x16x32_bf16(af[i], bf[j], acc[i][j], 0, 0, 0);
    }
  }
}

#define GEMM_PROLOGUE() \
  __shared__ __align__(16) u16 S[S_U16]; \
  u16* As = S; u16* Bs = S + 128 * LDK; \
  floatx4 acc[4][4]; \
  { floatx4 zv = {0.f, 0.f, 0.f, 0.f}; \
    _Pragma("unroll") for (int i = 0; i < 4; ++i) \
      _Pragma("unroll") for (int j = 0; j < 4; ++j) acc[i][j] = zv; } \
  const int tid = threadIdx.x; \
  const int lane = tid & 63, wv = tid >> 6; \
  const int wm = wv & 1, wn = wv >> 1, q = lane >> 4, l15 = lane & 15; \
  (void)lane;

// coalesced tile store: S[128][TS] bf16 -> dst rows (row stride 384 u16)
__device__ __forceinline__ void tile_store(const u16* S, u16* dst, int m0) {
  const int tid = threadIdx.x;
  const int col = (tid & 31) * 4, rowo = tid >> 5;
  #pragma unroll
  for (int rr = 0; rr < 16; ++rr) {
    int row = rr * 8 + rowo;
    *(u64*)(dst + (size_t)(m0 + row) * 384 + col) = *(const u64*)&S[row * TS + col];
  }
}

// GEMM1: h(bf16) @ lin_w_bf^T + lin_b -> xx (n<384), z (n>=384), bf16 channel-last
__global__ __launch_bounds__(256) void k_gemm_lin(const u16* __restrict__ A,
                                                  const u16* __restrict__ Bw,
                                                  const float* __restrict__ bias,
                                                  u16* __restrict__ xx, u16* __restrict__ z) {
  GEMM_PROLOGUE();
  const int id = xcd_swz(blockIdx.x, 2352);
  const int n0 = (id % 6) * 128, m0 = (id / 6) * 128;   // same-XCD ids share A-tile
  gemm_core(A, Bw, m0, n0, As, Bs, acc);
  __syncthreads();
  #pragma unroll
  for (int i = 0; i < 4; ++i)
    #pragma unroll
    for (int j = 0; j < 4; ++j) {
      int nl = wn * 64 + j * 16 + l15;
      float bb = bias[n0 + nl];
      #pragma unroll
      for (int r = 0; r < 4; ++r) {
        int ml = wm * 64 + i * 16 + q * 4 + r;
        S[ml * TS + nl] = f2bf(acc[i][j][r] + bb);
      }
    }
  __syncthreads();
  u16* dst = (n0 < 384) ? (xx + n0) : (z + (n0 - 384));
  tile_store(S, dst, m0);
}

// GEMM2: fe_bf16 @ tok_w_bf^T + tok_b -> gelu -> wave gain g (bf16)
__global__ __launch_bounds__(256) void k_gemm_tok(const u16* __restrict__ A,
                                                  const u16* __restrict__ Bw,
                                                  const float* __restrict__ bias,
                                                  const float* __restrict__ cs,
                                                  const float* __restrict__ al,
                                                  u16* __restrict__ g) {
  GEMM_PROLOGUE();
  const int id = xcd_swz(blockIdx.x, 1176);
  const int n0 = (id % 3) * 128, m0 = (id / 3) * 128;   // same-XCD ids share A-tile
  gemm_core(A, Bw, m0, n0, As, Bs, acc);
  const float c0 = cs[0], a0 = al[0];
  const float sc = (1.0f / (c0 + 1e-8f)) * (1.0f + 0.5f * a0);
  __syncthreads();
  #pragma unroll
  for (int i = 0; i < 4; ++i)
    #pragma unroll
    for (int j = 0; j < 4; ++j) {
      int nl = wn * 64 + j * 16 + l15;
      float bb = bias[n0 + nl];
      #pragma unroll
      for (int r = 0; r < 4; ++r) {
        int ml = wm * 64 + i * 16 + q * 4 + r;
        float v = acc[i][j][r] + bb;
        float t = gelu_fast(v);
        float ct = c0 * t;
        S[ml * TS + nl] = f2bf(__cosf(ct) + __sinf(ct) * sc);
      }
    }
  __syncthreads();
  tile_store(S, g + n0, m0);
}

// GEMM3: out_w_bf(M=channel) x A3(bf16, N=pixel) -> d_out[b,c,h,w] fp32 + out_b
__global__ __launch_bounds__(256) void k_gemm_out(const u16* __restrict__ A,
                                                  const u16* __restrict__ Bp,
                                                  const float* __restrict__ bias,
                                                  float* __restrict__ outp) {
  GEMM_PROLOGUE();
  const int id = xcd_swz(blockIdx.x, 1176);
  const int m0 = (id % 3) * 128, n0 = (id / 3) * 128;   // same-XCD ids share B-tile (A3)
  gemm_core(A, Bp, m0, n0, As, Bs, acc);
  #pragma unroll
  for (int i = 0; i < 4; ++i)
    #pragma unroll
    for (int j = 0; j < 4; ++j) {
      int t = n0 + wn * 64 + j * 16 + l15;      // pixel index
      int b = t / 3136, p = t - b * 3136;
      #pragma unroll
      for (int r = 0; r < 4; ++r) {
        int m = m0 + wm * 64 + i * 16 + q * 4 + r;   // channel
        outp[((size_t)b * 384 + m) * 3136 + p] = acc[i][j][r] + bias[m];
      }
    }
}

// ---------------- DCT chain (fp32 math, bf16 storage, in-place) ----------------
// xx[b,h,w,c] -> u1[b,n,w,c] = sum_h Wd[n,h]*xx  (in-place)
__global__ __launch_bounds__(256) void k_dct_h(u16* __restrict__ xx,
                                               const float* __restrict__ Wd) {
  __shared__ float Xs[56 * 128];
  __shared__ float Ws[3136];
  const int w = blockIdx.x, cb = blockIdx.y * 128, b = blockIdx.z;
  const int tid = threadIdx.x;
  for (int i = tid; i < 3136; i += 256) Ws[i] = Wd[i];
  for (int i = tid; i < 56 * 64; i += 256) {
    int h = i >> 6, cu = i & 63;
    unsigned int p = *(const unsigned int*)(xx + ((size_t)(b * 56 + h) * 56 + w) * 384 + cb + cu * 2);
    bfp(p, Xs[h * 128 + cu * 2], Xs[h * 128 + cu * 2 + 1]);
  }
  __syncthreads();
  const int lane = tid & 63, wv = tid >> 6;
  float a0[14], a1[14];
  #pragma unroll
  for (int k = 0; k < 14; ++k) { a0[k] = 0.f; a1[k] = 0.f; }
  for (int h = 0; h < 56; ++h) {
    float x0 = Xs[h * 128 + 2 * lane];
    float x1 = Xs[h * 128 + 2 * lane + 1];
    #pragma unroll
    for (int k = 0; k < 14; ++k) {
      float wn = Ws[(wv + 4 * k) * 56 + h];
      a0[k] += wn * x0; a1[k] += wn * x1;
    }
  }
  #pragma unroll
  for (int k = 0; k < 14; ++k) {
    int n = wv + 4 * k;
    *(unsigned int*)(xx + ((size_t)(b * 56 + n) * 56 + w) * 384 + cb + 2 * lane) = packbf(a0[k], a1[k]);
  }
}

// fused: V = Wd @ u1[b,n] (over w); V *= g; y1[b,n] = Wd^T @ V (over m). In-place on u1.
__global__ __launch_bounds__(256) void k_mid(u16* __restrict__ u1,
                                             const u16* __restrict__ g,
                                             const float* __restrict__ Wd) {
  __shared__ float Us[56 * 64];
  __shared__ float Vs[56 * 64];
  __shared__ float Ws[3136];
  const int n = blockIdx.x, cb = blockIdx.y * 64, b = blockIdx.z;
  const int tid = threadIdx.x;
  for (int i = tid; i < 3136; i += 256) Ws[i] = Wd[i];
  for (int i = tid; i < 56 * 32; i += 256) {
    int ww = i >> 5, cu = i & 31;
    unsigned int p = *(const unsigned int*)(u1 + ((size_t)(b * 56 + n) * 56 + ww) * 384 + cb + cu * 2);
    bfp(p, Us[ww * 64 + cu * 2], Us[ww * 64 + cu * 2 + 1]);
  }
  __syncthreads();
  const int lane = tid & 63, wv = tid >> 6;
  {
    float a[14];
    #pragma unroll
    for (int k = 0; k < 14; ++k) a[k] = 0.f;
    for (int ww = 0; ww < 56; ++ww) {
      float xv = Us[ww * 64 + lane];
      #pragma unroll
      for (int k = 0; k < 14; ++k)
        a[k] += Ws[(wv + 4 * k) * 56 + ww] * xv;
    }
    #pragma unroll
    for (int k = 0; k < 14; ++k) Vs[(wv + 4 * k) * 64 + lane] = a[k];
  }
  __syncthreads();
  for (int i = tid; i < 56 * 32; i += 256) {
    int m = i >> 5, cu = i & 31;
    unsigned int p = *(const unsigned int*)(g + ((size_t)(b * 56 + n) * 56 + m) * 384 + cb + cu * 2);
    float g0, g1; bfp(p, g0, g1);
    Vs[m * 64 + cu * 2]     *= g0;
    Vs[m * 64 + cu * 2 + 1] *= g1;
  }
  __syncthreads();
  {
    float a[14];
    #pragma unroll
    for (int k = 0; k < 14; ++k) a[k] = 0.f;
    for (int m = 0; m < 56; ++m) {
      float xv = Vs[m * 64 + lane];
      #pragma unroll
      for (int k = 0; k < 14; ++k)
        a[k] += Ws[m * 56 + (wv + 4 * k)] * xv;   // Wd[m, yy]
    }
    #pragma unroll
    for (int k = 0; k < 14; ++k) {
      int yy = wv + 4 * k;
      u1[((size_t)(b * 56 + n) * 56 + yy) * 384 + cb + lane] = f2bf(a[k]);
    }
  }
}

// y1[b,n,yy,c] -> y2[b,x,yy,c] = sum_n Wd[n,x]*y1  (in-place)
__global__ __launch_bounds__(256) void k_idct_h(u16* __restrict__ y1,
                                                const float* __restrict__ Wd) {
  __shared__ float Ys[56 * 128];
  __shared__ float Ws[3136];
  const int yy = blockIdx.x, cb = blockIdx.y * 128, b = blockIdx.z;
  const int tid = threadIdx.x;
  for (int i = tid; i < 3136; i += 256) Ws[i] = Wd[i];
  for (int i = tid; i < 56 * 64; i += 256) {
    int nn = i >> 6, cu = i & 63;
    unsigned int p = *(const unsigned int*)(y1 + ((size_t)(b * 56 + nn) * 56 + yy) * 384 + cb + cu * 2);
    bfp(p, Ys[nn * 128 + cu * 2], Ys[nn * 128 + cu * 2 + 1]);
  }
  __syncthreads();
  const int lane = tid & 63, wv = tid >> 6;
  float a0[14], a1[14];
  #pragma unroll
  for (int k = 0; k < 14; ++k) { a0[k] = 0.f; a1[k] = 0.f; }
  for (int nn = 0; nn < 56; ++nn) {
    float x0 = Ys[nn * 128 + 2 * lane];
    float x1 = Ys[nn * 128 + 2 * lane + 1];
    #pragma unroll
    for (int k = 0; k < 14; ++k) {
      float wn = Ws[nn * 56 + (wv + 4 * k)];   // Wd[n, x]
      a0[k] += wn * x0; a1[k] += wn * x1;
    }
  }
  #pragma unroll
  for (int k = 0; k < 14; ++k) {
    int x = wv + 4 * k;
    *(unsigned int*)(y1 + ((size_t)(b * 56 + x) * 56 + yy) * 384 + cb + 2 * lane) = packbf(a0[k], a1[k]);
  }
}

// ---------------- LayerNorm + SiLU gate -> bf16 A3 (in-place over y2) ----------------
__global__ __launch_bounds__(256) void k_ln(u16* __restrict__ y2,
                                            const u16* __restrict__ z,
                                            const float* __restrict__ lgm,
                                            const float* __restrict__ lbt) {
  const int t = blockIdx.x * 4 + (threadIdx.x >> 6);
  const int lane = threadIdx.x & 63;
  u16* yr = y2 + (size_t)t * 384;
  const u16* zr = z + (size_t)t * 384;
  float v[6]; float s = 0.f, s2 = 0.f;
  #pragma unroll
  for (int k = 0; k < 3; ++k) {
    unsigned int p = *(const unsigned int*)(yr + 2 * lane + 128 * k);
    float f0, f1; bfp(p, f0, f1);
    v[2 * k] = f0; v[2 * k + 1] = f1;
    s += f0 + f1; s2 += f0 * f0 + f1 * f1;
  }
  #pragma unroll
  for (int off = 32; off >= 1; off >>= 1) {
    s  += __shfl_xor(s, off, 64);
    s2 += __shfl_xor(s2, off, 64);
  }
  const float mu  = s * (1.0f / 384.0f);
  const float var = s2 * (1.0f / 384.0f) - mu * mu;
  const float inv = rsqrtf(var + 1e-5f);
  #pragma unroll
  for (int k = 0; k < 3; ++k) {
    int c = 2 * lane + 128 * k;
    float z0, z1;
    bfp(*(const unsigned int*)(zr + c), z0, z1);
    float yn0 = (v[2 * k]     - mu) * inv * lgm[c]     + lbt[c];
    float yn1 = (v[2 * k + 1] - mu) * inv * lgm[c + 1] + lbt[c + 1];
    float ga0 = z0 / (1.0f + __expf(-z0));
    float ga1 = z1 / (1.0f + __expf(-z1));
    *(unsigned int*)(yr + c) = packbf(yn0 * ga0, yn1 * ga1);
  }
}

// ---------------- launch ----------------
extern "C" void kernel_launch(void* const* d_in, const int* in_sizes, int n_in,
                              void* d_out, int out_size, void* d_ws, size_t ws_size,
                              hipStream_t stream) {
  const float* x     = (const float*)d_in[0];
  const float* fe    = (const float*)d_in[1];
  const float* dw_w  = (const float*)d_in[2];
  const float* dw_b  = (const float*)d_in[3];
  const float* lin_w = (const float*)d_in[4];
  const float* lin_b = (const float*)d_in[5];
  const float* tok_w = (const float*)d_in[6];
  const float* tok_b = (const float*)d_in[7];
  const float* ln_g  = (const float*)d_in[8];
  const float* ln_b  = (const float*)d_in[9];
  const float* out_w = (const float*)d_in[10];
  const float* out_b = (const float*)d_in[11];
  const float* cs    = (const float*)d_in[12];
  const float* al    = (const float*)d_in[13];
  float* outp = (float*)d_out;
  char* ws = (char*)d_ws;

  float* Wd = (float*)(ws + 0);                        // 12,544 B (pad to 16 KiB)
  u16* SA = (u16*)(ws + 16384);                        // h, then g
  u16* SB = (u16*)(ws + 16384 + 38535168);             // xx -> u1 -> y1 -> y2 -> A3 (in-place chain)
  u16* SC = (u16*)(ws + 16384 + 2 * (size_t)38535168); // z
  u16* Wbf = (u16*)(ws + 16384 + 3 * (size_t)38535168);// lin_w|tok_w|out_w bf16 (1,179,648 B)
  u16* FEbf = (u16*)d_out;                             // fe bf16 scratch (38.5 MB <= 77 MB out);
                                                       // fully consumed before k_gemm_out overwrites

  k_prep<<<dim3(19396), dim3(256), 0, stream>>>(fe, lin_w, tok_w, out_w, FEbf, Wbf, Wd);
  k_conv<<<dim3(56, 6, 16), dim3(256), 0, stream>>>(x, dw_w, dw_b, SA);            // h in SA
  k_gemm_lin<<<dim3(2352), dim3(256), 0, stream>>>(SA, Wbf, lin_b, SB, SC);        // xx in SB, z in SC
  k_gemm_tok<<<dim3(1176), dim3(256), 0, stream>>>(FEbf, Wbf + 294912, tok_b, cs, al, SA); // g in SA
  k_dct_h<<<dim3(56, 3, 16), dim3(256), 0, stream>>>(SB, Wd);                      // xx -> u1
  k_mid<<<dim3(56, 6, 16), dim3(256), 0, stream>>>(SB, SA, Wd);                    // u1,g -> y1
  k_idct_h<<<dim3(56, 3, 16), dim3(256), 0, stream>>>(SB, Wd);                     // y1 -> y2
  k_ln<<<dim3(12544), dim3(256), 0, stream>>>(SB, SC, ln_g, ln_b);                 // y2,z -> A3
  k_gemm_out<<<dim3(1176), dim3(256), 0, stream>>>(Wbf + 442368, SB, out_b, outp);
}

// Round 4
// 622.833 us; speedup vs baseline: 1.7193x; 1.2092x over previous
//
#include <hip/hip_runtime.h>
#include <cstdint>
#include <cstddef>

typedef __attribute__((ext_vector_type(8))) short short8;
typedef __attribute__((ext_vector_type(4))) float floatx4;
typedef unsigned short u16;
typedef unsigned long long u64;

__device__ __forceinline__ float bf2f(u16 u) {
  union { unsigned int i; float f; } v; v.i = ((unsigned int)u) << 16; return v.f;
}
__device__ __forceinline__ u16 f2bf(float f) {
  union { float f; unsigned int u; } v; v.f = f;
  return (u16)((v.u + 0x7fffu + ((v.u >> 16) & 1u)) >> 16);
}
__device__ __forceinline__ void bfp(unsigned int p, float& x, float& y) {
  union { unsigned int i; float f; } a, b;
  a.i = p << 16; b.i = p & 0xffff0000u;
  x = a.f; y = b.f;
}
__device__ __forceinline__ unsigned int packbf(float a, float b) {
  return (unsigned int)f2bf(a) | ((unsigned int)f2bf(b) << 16);
}
__device__ __forceinline__ u64 pack4(float a, float b, float c, float d) {
  return (u64)f2bf(a) | ((u64)f2bf(b) << 16) | ((u64)f2bf(c) << 32) | ((u64)f2bf(d) << 48);
}

typedef __attribute__((address_space(1))) const unsigned int gu32;
typedef __attribute__((address_space(3))) unsigned int lu32;
__device__ __forceinline__ void gl2lds16(const void* g, void* l) {
  __builtin_amdgcn_global_load_lds((gu32*)g, (lu32*)l, 16, 0, 0);
}

// XCD-chunked swizzle: consecutive work-ids land on the SAME XCD L2.
__device__ __forceinline__ int xcd_swz(int id, int nwg) {
  int cpx = nwg >> 3;                 // nwg % 8 == 0 for all our grids
  return (id & 7) * cpx + (id >> 3);
}

// exact-gelu via A&S 7.1.26 erf rational (|err| < 1.5e-7), one native exp
__device__ __forceinline__ float gelu_fast(float v) {
  float xg = v * 0.7071067811865476f;
  float ax = fabsf(xg);
  float tr = __builtin_amdgcn_rcpf(fmaf(0.3275911f, ax, 1.0f));
  float pl = tr * (0.254829592f + tr * (-0.284496736f + tr * (1.421413741f +
             tr * (-1.453152027f + tr * 1.061405429f))));
  float er = 1.0f - pl * __expf(-xg * xg);
  er = (xg < 0.f) ? -er : er;
  return 0.5f * v * (1.0f + er);
}

// ---------------- fused prep: fe fp32->bf16, weights fp32->bf16, DCT matrix ----------------
#define FE_F4 4816896    // 16*3136*384 / 4
#define W_F4  147456     // (2C*C + C*C + C*C) / 4 = 589824/4
__global__ __launch_bounds__(256) void k_prep(const float* __restrict__ fe,
                                              const float* __restrict__ lw,
                                              const float* __restrict__ tw,
                                              const float* __restrict__ ow,
                                              u16* __restrict__ febf,
                                              u16* __restrict__ wbf,
                                              float* __restrict__ Wd) {
  int gid = blockIdx.x * 256 + threadIdx.x;
  if (gid < FE_F4) {
    float4 v = ((const float4*)fe)[gid];
    *(u64*)&febf[gid * 4] = pack4(v.x, v.y, v.z, v.w);
    return;
  }
  gid -= FE_F4;
  if (gid < W_F4) {
    const float* src; int off; int i = gid;
    if (i < 73728)        { src = lw; off = 0; }
    else if (i < 110592)  { src = tw; off = 294912; i -= 73728; }
    else                  { src = ow; off = 442368; i -= 110592; }
    float4 v = ((const float4*)src)[i];
    *(u64*)&wbf[off + i * 4] = pack4(v.x, v.y, v.z, v.w);
    return;
  }
  gid -= W_F4;
  if (gid < 784) {
    #pragma unroll
    for (int j = 0; j < 4; ++j) {
      int i = gid * 4 + j;
      int n = i / 56, x = i - n * 56;
      float v = cosf(3.14159265358979323846f * (float)n * ((float)x + 0.5f) / 56.0f)
                * 0.1889822365046136f;            // sqrt(2/56)
      if (n == 0) v *= 0.7071067811865476f;
      Wd[i] = v;
    }
  }
}

// ---------------- depthwise conv 3x3, NCHW fp32 -> channel-last bf16 ----------------
// Block: 4 output rows x 32 channels x 1 batch. LDS transposed [6 rows][60 cols][33 ch]:
// lanes=channels -> conflict-free reads; cols 56..59 zeroed + 33-float guard make the
// -1/+1 column taps read zeros branch-free. Staging: contiguous float4 (6 rows of a
// plane are one 1344B span).
__global__ __launch_bounds__(256) void k_conv(const float* __restrict__ x,
                                              const float* __restrict__ w9,
                                              const float* __restrict__ b1,
                                              u16* __restrict__ hbf) {
  __shared__ float xsr[33 + 6 * 60 * 33];     // guard(33) + [row][col][ch]
  float* xs = xsr + 33;
  const int y0 = blockIdx.x * 4, c0 = blockIdx.y * 32, b = blockIdx.z;
  const int tid = threadIdx.x;
  // zero guard + tail cols 56..59 (contiguous 132 floats per row)
  for (int i = tid; i < 33; i += 256) xsr[i] = 0.f;
  for (int i = tid; i < 792; i += 256) {
    int row = i / 132, j = i - row * 132;
    xs[(row * 60 + 56) * 33 + j] = 0.f;
  }
  // stage 32ch x 6 rows x 56 cols as float4 (2688 items)
  for (int i = tid; i < 2688; i += 256) {
    int ch = i / 84, rem = i - ch * 84;
    int row = rem / 14, q4 = rem - row * 14;
    int gy = y0 + row - 1;
    float4 v = {0.f, 0.f, 0.f, 0.f};
    if (gy >= 0 && gy < 56)
      v = *(const float4*)(x + ((size_t)(b * 384 + c0 + ch) * 56 + gy) * 56 + q4 * 4);
    int base = (row * 60 + q4 * 4) * 33 + ch;
    xs[base] = v.x; xs[base + 33] = v.y; xs[base + 66] = v.z; xs[base + 99] = v.w;
  }
  __syncthreads();
  const int ch = tid & 31, g = tid >> 5;
  const int r = g & 3, pxb = (g >> 2) * 28;   // output row y0+r, 28-px half
  float wr[9];
  #pragma unroll
  for (int k = 0; k < 9; ++k) wr[k] = w9[(c0 + ch) * 9 + k];
  const float br = b1[c0 + ch];
  float p0[3], p1[3];
  #pragma unroll
  for (int dy = 0; dy < 3; ++dy) {
    p0[dy] = xs[((r + dy) * 60 + pxb - 1) * 33 + ch];
    p1[dy] = xs[((r + dy) * 60 + pxb) * 33 + ch];
  }
  u16* orow = hbf + ((size_t)b * 3136 + (y0 + r) * 56) * 384 + c0 + ch;
  #pragma unroll 4
  for (int px = pxb; px < pxb + 28; ++px) {
    float p2[3];
    #pragma unroll
    for (int dy = 0; dy < 3; ++dy) p2[dy] = xs[((r + dy) * 60 + px + 1) * 33 + ch];
    float a = br;
    #pragma unroll
    for (int dy = 0; dy < 3; ++dy) {       // same 9-term order as before: dy outer, dx inner
      a += wr[dy * 3 + 0] * p0[dy];
      a += wr[dy * 3 + 1] * p1[dy];
      a += wr[dy * 3 + 2] * p2[dy];
    }
    orow[(size_t)px * 384] = f2bf(a);
    #pragma unroll
    for (int dy = 0; dy < 3; ++dy) { p0[dy] = p1[dy]; p1[dy] = p2[dy]; }
  }
}

// ---------------- MFMA GEMM core, 128x128 tile, K=384, 2 barriers/K-step ----------------
#define LDK 64
#define TS 132
#define S_U16 16896   // max(2*128*64, 128*132) -> 33792 B

// bf16 source, direct-to-LDS DMA; XOR-permuted GLOBAL column => swizzled LDS content.
__device__ __forceinline__ void stage_dma(const u16* __restrict__ src, int base, int kt,
                                          u16* __restrict__ buf, int tid) {
  const int r0 = tid >> 3, c8 = tid & 7;
  const int scol = (c8 ^ (r0 & 7)) << 3;
  #pragma unroll
  for (int p = 0; p < 4; ++p) {
    int row = p * 32 + r0;
    gl2lds16(src + (size_t)(base + row) * 384 + kt + scol, &buf[row * LDK + (c8 << 3)]);
  }
}

__device__ __forceinline__ short8 frag_read(const u16* buf, int r, int u) {
  return *(const short8*)&buf[r * LDK + (((u ^ (r & 7)) << 3))];
}

__device__ __forceinline__ void gemm_core(const u16* __restrict__ Ap,
                                          const u16* __restrict__ Bp,
                                          int m0, int n0, u16* As, u16* Bs,
                                          floatx4 acc[4][4]) {
  const int tid = threadIdx.x;
  const int lane = tid & 63, wv = tid >> 6;
  const int wm = wv & 1, wn = wv >> 1;
  const int q = lane >> 4, l15 = lane & 15;
  for (int kt = 0; kt < 384; kt += 64) {
    __syncthreads();                       // prev compute done reading LDS
    stage_dma(Bp, n0, kt, Bs, tid);
    stage_dma(Ap, m0, kt, As, tid);
    __syncthreads();                       // drains vmcnt+lgkmcnt: tiles ready
    #pragma unroll
    for (int kc = 0; kc < 64; kc += 32) {
      short8 af[4], bf[4];
      #pragma unroll
      for (int i = 0; i < 4; ++i) {
        af[i] = frag_read(As, wm * 64 + i * 16 + l15, (kc >> 3) + q);
        bf[i] = frag_read(Bs, wn * 64 + i * 16 + l15, (kc >> 3) + q);
      }
      #pragma unroll
      for (int i = 0; i < 4; ++i)
        #pragma unroll
        for (int j = 0; j < 4; ++j)
          acc[i][j] = __builtin_amdgcn_mfma_f32_16x16x32_bf16(af[i], bf[j], acc[i][j], 0, 0, 0);
    }
  }
}

#define GEMM_PROLOGUE() \
  __shared__ __align__(16) u16 S[S_U16]; \
  u16* As = S; u16* Bs = S + 128 * LDK; \
  floatx4 acc[4][4]; \
  { floatx4 zv = {0.f, 0.f, 0.f, 0.f}; \
    _Pragma("unroll") for (int i = 0; i < 4; ++i) \
      _Pragma("unroll") for (int j = 0; j < 4; ++j) acc[i][j] = zv; } \
  const int tid = threadIdx.x; \
  const int lane = tid & 63, wv = tid >> 6; \
  const int wm = wv & 1, wn = wv >> 1, q = lane >> 4, l15 = lane & 15; \
  (void)lane;

// coalesced tile store: S[128][TS] bf16 -> dst rows (row stride 384 u16)
__device__ __forceinline__ void tile_store(const u16* S, u16* dst, int m0) {
  const int tid = threadIdx.x;
  const int col = (tid & 31) * 4, rowo = tid >> 5;
  #pragma unroll
  for (int rr = 0; rr < 16; ++rr) {
    int row = rr * 8 + rowo;
    *(u64*)(dst + (size_t)(m0 + row) * 384 + col) = *(const u64*)&S[row * TS + col];
  }
}

// GEMM1: h(bf16) @ lin_w_bf^T + lin_b -> xx (n<384), z (n>=384), bf16 channel-last
__global__ __launch_bounds__(256) void k_gemm_lin(const u16* __restrict__ A,
                                                  const u16* __restrict__ Bw,
                                                  const float* __restrict__ bias,
                                                  u16* __restrict__ xx, u16* __restrict__ z) {
  GEMM_PROLOGUE();
  const int id = xcd_swz(blockIdx.x, 2352);
  const int n0 = (id % 6) * 128, m0 = (id / 6) * 128;   // same-XCD ids share A-tile
  gemm_core(A, Bw, m0, n0, As, Bs, acc);
  __syncthreads();
  #pragma unroll
  for (int i = 0; i < 4; ++i)
    #pragma unroll
    for (int j = 0; j < 4; ++j) {
      int nl = wn * 64 + j * 16 + l15;
      float bb = bias[n0 + nl];
      #pragma unroll
      for (int r = 0; r < 4; ++r) {
        int ml = wm * 64 + i * 16 + q * 4 + r;
        S[ml * TS + nl] = f2bf(acc[i][j][r] + bb);
      }
    }
  __syncthreads();
  u16* dst = (n0 < 384) ? (xx + n0) : (z + (n0 - 384));
  tile_store(S, dst, m0);
}

// GEMM2: fe_bf16 @ tok_w_bf^T + tok_b -> gelu -> wave gain g (bf16)
__global__ __launch_bounds__(256) void k_gemm_tok(const u16* __restrict__ A,
                                                  const u16* __restrict__ Bw,
                                                  const float* __restrict__ bias,
                                                  const float* __restrict__ cs,
                                                  const float* __restrict__ al,
                                                  u16* __restrict__ g) {
  GEMM_PROLOGUE();
  const int id = xcd_swz(blockIdx.x, 1176);
  const int n0 = (id % 3) * 128, m0 = (id / 3) * 128;   // same-XCD ids share A-tile
  gemm_core(A, Bw, m0, n0, As, Bs, acc);
  const float c0 = cs[0], a0 = al[0];
  const float sc = (1.0f / (c0 + 1e-8f)) * (1.0f + 0.5f * a0);
  __syncthreads();
  #pragma unroll
  for (int i = 0; i < 4; ++i)
    #pragma unroll
    for (int j = 0; j < 4; ++j) {
      int nl = wn * 64 + j * 16 + l15;
      float bb = bias[n0 + nl];
      #pragma unroll
      for (int r = 0; r < 4; ++r) {
        int ml = wm * 64 + i * 16 + q * 4 + r;
        float v = acc[i][j][r] + bb;
        float t = gelu_fast(v);
        float ct = c0 * t;
        S[ml * TS + nl] = f2bf(__cosf(ct) + __sinf(ct) * sc);
      }
    }
  __syncthreads();
  tile_store(S, g + n0, m0);
}

// GEMM3: out_w_bf(M=channel) x A3(bf16, N=pixel) -> d_out[b,c,h,w] fp32 + out_b
__global__ __launch_bounds__(256) void k_gemm_out(const u16* __restrict__ A,
                                                  const u16* __restrict__ Bp,
                                                  const float* __restrict__ bias,
                                                  float* __restrict__ outp) {
  GEMM_PROLOGUE();
  const int id = xcd_swz(blockIdx.x, 1176);
  const int m0 = (id % 3) * 128, n0 = (id / 3) * 128;   // same-XCD ids share B-tile (A3)
  gemm_core(A, Bp, m0, n0, As, Bs, acc);
  #pragma unroll
  for (int i = 0; i < 4; ++i)
    #pragma unroll
    for (int j = 0; j < 4; ++j) {
      int t = n0 + wn * 64 + j * 16 + l15;      // pixel index
      int b = t / 3136, p = t - b * 3136;
      #pragma unroll
      for (int r = 0; r < 4; ++r) {
        int m = m0 + wm * 64 + i * 16 + q * 4 + r;   // channel
        outp[((size_t)b * 384 + m) * 3136 + p] = acc[i][j][r] + bias[m];
      }
    }
}

// ---------------- DCT chain (fp32 math, bf16 storage, in-place) ----------------
// xx[b,h,w,c] -> u1[b,n,w,c] = sum_h Wd[n,h]*xx  (in-place)
__global__ __launch_bounds__(256) void k_dct_h(u16* __restrict__ xx,
                                               const float* __restrict__ Wd) {
  __shared__ float Xs[56 * 128];
  __shared__ float Ws[3136];
  const int w = blockIdx.x, cb = blockIdx.y * 128, b = blockIdx.z;
  const int tid = threadIdx.x;
  for (int i = tid; i < 3136; i += 256) Ws[i] = Wd[i];
  for (int i = tid; i < 56 * 64; i += 256) {
    int h = i >> 6, cu = i & 63;
    unsigned int p = *(const unsigned int*)(xx + ((size_t)(b * 56 + h) * 56 + w) * 384 + cb + cu * 2);
    bfp(p, Xs[h * 128 + cu * 2], Xs[h * 128 + cu * 2 + 1]);
  }
  __syncthreads();
  const int lane = tid & 63, wv = tid >> 6;
  float a0[14], a1[14];
  #pragma unroll
  for (int k = 0; k < 14; ++k) { a0[k] = 0.f; a1[k] = 0.f; }
  for (int h = 0; h < 56; ++h) {
    float x0 = Xs[h * 128 + 2 * lane];
    float x1 = Xs[h * 128 + 2 * lane + 1];
    #pragma unroll
    for (int k = 0; k < 14; ++k) {
      float wn = Ws[(wv + 4 * k) * 56 + h];
      a0[k] += wn * x0; a1[k] += wn * x1;
    }
  }
  #pragma unroll
  for (int k = 0; k < 14; ++k) {
    int n = wv + 4 * k;
    *(unsigned int*)(xx + ((size_t)(b * 56 + n) * 56 + w) * 384 + cb + 2 * lane) = packbf(a0[k], a1[k]);
  }
}

// fused: V = Wd @ u1[b,n] (over w); V *= g; y1[b,n] = Wd^T @ V (over m). In-place on u1.
__global__ __launch_bounds__(256) void k_mid(u16* __restrict__ u1,
                                             const u16* __restrict__ g,
                                             const float* __restrict__ Wd) {
  __shared__ float Us[56 * 64];
  __shared__ float Vs[56 * 64];
  __shared__ float Ws[3136];
  const int n = blockIdx.x, cb = blockIdx.y * 64, b = blockIdx.z;
  const int tid = threadIdx.x;
  for (int i = tid; i < 3136; i += 256) Ws[i] = Wd[i];
  for (int i = tid; i < 56 * 32; i += 256) {
    int ww = i >> 5, cu = i & 31;
    unsigned int p = *(const unsigned int*)(u1 + ((size_t)(b * 56 + n) * 56 + ww) * 384 + cb + cu * 2);
    bfp(p, Us[ww * 64 + cu * 2], Us[ww * 64 + cu * 2 + 1]);
  }
  __syncthreads();
  const int lane = tid & 63, wv = tid >> 6;
  {
    float a[14];
    #pragma unroll
    for (int k = 0; k < 14; ++k) a[k] = 0.f;
    for (int ww = 0; ww < 56; ++ww) {
      float xv = Us[ww * 64 + lane];
      #pragma unroll
      for (int k = 0; k < 14; ++k)
        a[k] += Ws[(wv + 4 * k) * 56 + ww] * xv;
    }
    #pragma unroll
    for (int k = 0; k < 14; ++k) Vs[(wv + 4 * k) * 64 + lane] = a[k];
  }
  __syncthreads();
  for (int i = tid; i < 56 * 32; i += 256) {
    int m = i >> 5, cu = i & 31;
    unsigned int p = *(const unsigned int*)(g + ((size_t)(b * 56 + n) * 56 + m) * 384 + cb + cu * 2);
    float g0, g1; bfp(p, g0, g1);
    Vs[m * 64 + cu * 2]     *= g0;
    Vs[m * 64 + cu * 2 + 1] *= g1;
  }
  __syncthreads();
  {
    float a[14];
    #pragma unroll
    for (int k = 0; k < 14; ++k) a[k] = 0.f;
    for (int m = 0; m < 56; ++m) {
      float xv = Vs[m * 64 + lane];
      #pragma unroll
      for (int k = 0; k < 14; ++k)
        a[k] += Ws[m * 56 + (wv + 4 * k)] * xv;   // Wd[m, yy]
    }
    #pragma unroll
    for (int k = 0; k < 14; ++k) {
      int yy = wv + 4 * k;
      u1[((size_t)(b * 56 + n) * 56 + yy) * 384 + cb + lane] = f2bf(a[k]);
    }
  }
}

// y1[b,n,yy,c] -> y2[b,x,yy,c] = sum_n Wd[n,x]*y1  (in-place)
__global__ __launch_bounds__(256) void k_idct_h(u16* __restrict__ y1,
                                                const float* __restrict__ Wd) {
  __shared__ float Ys[56 * 128];
  __shared__ float Ws[3136];
  const int yy = blockIdx.x, cb = blockIdx.y * 128, b = blockIdx.z;
  const int tid = threadIdx.x;
  for (int i = tid; i < 3136; i += 256) Ws[i] = Wd[i];
  for (int i = tid; i < 56 * 64; i += 256) {
    int nn = i >> 6, cu = i & 63;
    unsigned int p = *(const unsigned int*)(y1 + ((size_t)(b * 56 + nn) * 56 + yy) * 384 + cb + cu * 2);
    bfp(p, Ys[nn * 128 + cu * 2], Ys[nn * 128 + cu * 2 + 1]);
  }
  __syncthreads();
  const int lane = tid & 63, wv = tid >> 6;
  float a0[14], a1[14];
  #pragma unroll
  for (int k = 0; k < 14; ++k) { a0[k] = 0.f; a1[k] = 0.f; }
  for (int nn = 0; nn < 56; ++nn) {
    float x0 = Ys[nn * 128 + 2 * lane];
    float x1 = Ys[nn * 128 + 2 * lane + 1];
    #pragma unroll
    for (int k = 0; k < 14; ++k) {
      float wn = Ws[nn * 56 + (wv + 4 * k)];   // Wd[n, x]
      a0[k] += wn * x0; a1[k] += wn * x1;
    }
  }
  #pragma unroll
  for (int k = 0; k < 14; ++k) {
    int x = wv + 4 * k;
    *(unsigned int*)(y1 + ((size_t)(b * 56 + x) * 56 + yy) * 384 + cb + 2 * lane) = packbf(a0[k], a1[k]);
  }
}

// ---------------- LayerNorm + SiLU gate -> bf16 A3 (in-place over y2) ----------------
__global__ __launch_bounds__(256) void k_ln(u16* __restrict__ y2,
                                            const u16* __restrict__ z,
                                            const float* __restrict__ lgm,
                                            const float* __restrict__ lbt) {
  const int t = blockIdx.x * 4 + (threadIdx.x >> 6);
  const int lane = threadIdx.x & 63;
  u16* yr = y2 + (size_t)t * 384;
  const u16* zr = z + (size_t)t * 384;
  float v[6]; float s = 0.f, s2 = 0.f;
  #pragma unroll
  for (int k = 0; k < 3; ++k) {
    unsigned int p = *(const unsigned int*)(yr + 2 * lane + 128 * k);
    float f0, f1; bfp(p, f0, f1);
    v[2 * k] = f0; v[2 * k + 1] = f1;
    s += f0 + f1; s2 += f0 * f0 + f1 * f1;
  }
  #pragma unroll
  for (int off = 32; off >= 1; off >>= 1) {
    s  += __shfl_xor(s, off, 64);
    s2 += __shfl_xor(s2, off, 64);
  }
  const float mu  = s * (1.0f / 384.0f);
  const float var = s2 * (1.0f / 384.0f) - mu * mu;
  const float inv = rsqrtf(var + 1e-5f);
  #pragma unroll
  for (int k = 0; k < 3; ++k) {
    int c = 2 * lane + 128 * k;
    float z0, z1;
    bfp(*(const unsigned int*)(zr + c), z0, z1);
    float yn0 = (v[2 * k]     - mu) * inv * lgm[c]     + lbt[c];
    float yn1 = (v[2 * k + 1] - mu) * inv * lgm[c + 1] + lbt[c + 1];
    float ga0 = z0 / (1.0f + __expf(-z0));
    float ga1 = z1 / (1.0f + __expf(-z1));
    *(unsigned int*)(yr + c) = packbf(yn0 * ga0, yn1 * ga1);
  }
}

// ---------------- launch ----------------
extern "C" void kernel_launch(void* const* d_in, const int* in_sizes, int n_in,
                              void* d_out, int out_size, void* d_ws, size_t ws_size,
                              hipStream_t stream) {
  const float* x     = (const float*)d_in[0];
  const float* fe    = (const float*)d_in[1];
  const float* dw_w  = (const float*)d_in[2];
  const float* dw_b  = (const float*)d_in[3];
  const float* lin_w = (const float*)d_in[4];
  const float* lin_b = (const float*)d_in[5];
  const float* tok_w = (const float*)d_in[6];
  const float* tok_b = (const float*)d_in[7];
  const float* ln_g  = (const float*)d_in[8];
  const float* ln_b  = (const float*)d_in[9];
  const float* out_w = (const float*)d_in[10];
  const float* out_b = (const float*)d_in[11];
  const float* cs    = (const float*)d_in[12];
  const float* al    = (const float*)d_in[13];
  float* outp = (float*)d_out;
  char* ws = (char*)d_ws;

  float* Wd = (float*)(ws + 0);                        // 12,544 B (pad to 16 KiB)
  u16* SA = (u16*)(ws + 16384);                        // h, then g
  u16* SB = (u16*)(ws + 16384 + 38535168);             // xx -> u1 -> y1 -> y2 -> A3 (in-place chain)
  u16* SC = (u16*)(ws + 16384 + 2 * (size_t)38535168); // z
  u16* Wbf = (u16*)(ws + 16384 + 3 * (size_t)38535168);// lin_w|tok_w|out_w bf16 (1,179,648 B)
  u16* FEbf = (u16*)d_out;                             // fe bf16 scratch (38.5 MB <= 77 MB out);
                                                       // fully consumed before k_gemm_out overwrites

  k_prep<<<dim3(19396), dim3(256), 0, stream>>>(fe, lin_w, tok_w, out_w, FEbf, Wbf, Wd);
  k_conv<<<dim3(14, 12, 16), dim3(256), 0, stream>>>(x, dw_w, dw_b, SA);           // h in SA
  k_gemm_lin<<<dim3(2352), dim3(256), 0, stream>>>(SA, Wbf, lin_b, SB, SC);        // xx in SB, z in SC
  k_gemm_tok<<<dim3(1176), dim3(256), 0, stream>>>(FEbf, Wbf + 294912, tok_b, cs, al, SA); // g in SA
  k_dct_h<<<dim3(56, 3, 16), dim3(256), 0, stream>>>(SB, Wd);                      // xx -> u1
  k_mid<<<dim3(56, 6, 16), dim3(256), 0, stream>>>(SB, SA, Wd);                    // u1,g -> y1
  k_idct_h<<<dim3(56, 3, 16), dim3(256), 0, stream>>>(SB, Wd);                     // y1 -> y2
  k_ln<<<dim3(12544), dim3(256), 0, stream>>>(SB, SC, ln_g, ln_b);                 // y2,z -> A3
  k_gemm_out<<<dim3(1176), dim3(256), 0, stream>>>(Wbf + 442368, SB, out_b, outp);
}